// Round 13
// baseline (232.875 us; speedup 1.0000x reference)
//
#include <hip/hip_runtime.h>
#include <math.h>

// ---- problem constants ----
#define DIMC   256
#define HID    680
#define CHN    1360
#define HP     14
#define WP     14
#define P      196
#define POSI   4
#define INTER  64
#define BATCH  64
#define KPAD   704          // 680 padded to 22*32
#define OUTCH  12240        // CHN*9
#define MW     1408         // per-k-plane channel pad
#define MTOT   12672        // 9*MW
#define KIM    576          // INTER*9
#define MPADIN 1408         // 1360 padded to 11*128
#define EPSLN  1e-5f

typedef __attribute__((ext_vector_type(8))) short short8;
typedef __attribute__((ext_vector_type(4))) short short4v;
typedef __attribute__((ext_vector_type(4))) float f32x4;

// ---- workspace layout (bytes) ----
#define OFS_WBIN  0u                  // 1408*256*2   = 720896
#define OFS_WBOUT 720896u             // 256*704*2    = 360448
#define OFS_XT    1081344u            // 64*196*256*2 = 6422528
#define OFS_V0    7503872u            // 12544*4
#define OFS_V1    7554048u            // 12544*4
#define OFS_V2    7604224u            // 12544*4
#define OFS_WGTT  7654656u            // 196*9*1360*2 = 4798080
#define OFS_H1T   12452736u           // 64*196*1360*2 = 34127872
#define OFS_IMC   64242560u           // 196*576*2     = 225792
#define OFS_WFB   64468352u           // 9*1408*576*2  = 14598144
#define OFS_PST   79066496u           // partial LN stats (end ~79.1MB)

__device__ __forceinline__ unsigned short f2bf(float f) {
    union { float f; unsigned u; } v; v.f = f;
    unsigned u = v.u;
    return (unsigned short)((u + 0x7FFFu + ((u >> 16) & 1u)) >> 16);   // RNE
}
__device__ __forceinline__ float bf2f(unsigned short h) {
    union { unsigned u; float f; } v; v.u = ((unsigned)h) << 16; return v.f;
}

// async 16B global->LDS (wave-uniform LDS base + lane*16; global src may be per-lane)
__device__ __forceinline__ void gl2lds16(const unsigned short* g, unsigned short* l) {
    __builtin_amdgcn_global_load_lds(
        (const __attribute__((address_space(1))) unsigned int*)g,
        (__attribute__((address_space(3))) unsigned int*)l, 16, 0, 0);
}
// BK=64 tile: row stride 64, 8 slots of 16B, logical piece lp in 0..7
__device__ __forceinline__ short8 fragld64(const unsigned short* S, int row, int lp) {
    int slot = ((row >> 1) + lp) & 7;
    return *(const short8*)(S + row * 64 + slot * 8);
}

__device__ __forceinline__ void block_reduce2(float& s, float& ss, float* red, int tid, int nthreads) {
    #pragma unroll
    for (int off = 32; off > 0; off >>= 1) {
        s  += __shfl_down(s, off);
        ss += __shfl_down(ss, off);
    }
    int wid = tid >> 6, nw = nthreads >> 6;
    if ((tid & 63) == 0) { red[wid*2] = s; red[wid*2+1] = ss; }
    __syncthreads();
    if (tid == 0) {
        float S = 0.f, SS = 0.f;
        for (int i = 0; i < nw; i++) { S += red[i*2]; SS += red[i*2+1]; }
        red[0] = S; red[1] = SS;
    }
    __syncthreads();
    s = red[0]; ss = red[1];
}

// sum 49 per-block partial (s,ss) pairs — uniform addresses -> scalar loads, unrolled
__device__ __forceinline__ void sum_pstat(const float* __restrict__ pstat, int base,
                                          float& s, float& ss) {
    s = 0.f; ss = 0.f;
    #pragma unroll
    for (int i = 0; i < 49; i++) {
        s  += pstat[base + 2*i];
        ss += pstat[base + 2*i + 1];
    }
}

// ================= fused preamble: conv0 (49 blocks, FIRST) + pure streaming ============
#define NWIN  (MPADIN*DIMC)
#define NWOUT (DIMC*KPAD)
#define XT0   49
#define WF0   561
#define C0    2343
#define IMZ0  2475
#define PRE_BLKS 2489

__global__ __launch_bounds__(256) void k_pre(const float* __restrict__ Win,
                                             const float* __restrict__ Wout,
                                             const float* __restrict__ x,
                                             const float* __restrict__ wf,
                                             const float* __restrict__ posi,
                                             const float* __restrict__ w0,
                                             unsigned short* __restrict__ Wbin,
                                             unsigned short* __restrict__ Wbout,
                                             unsigned short* __restrict__ Xt,
                                             unsigned short* __restrict__ wfb,
                                             unsigned short* __restrict__ imc,
                                             float* __restrict__ v0,
                                             float* __restrict__ pstat) {
    __shared__ __align__(16) float smem[6304];       // 25.2 KB (xt tile / conv0 ppad+red)
    int bid = blockIdx.x, tid = threadIdx.x;
    if (bid < XT0) {
        // ---- conv0: posi (staged padded) * w0 -> v0; partial stats to pstat slots ----
        float (*ppad)[16][16] = (float(*)[16][16])smem;          // 4*256 floats
        float* red = smem + 1024;                                // 16 floats
        for (int i = tid; i < POSI * 256; i += 256) {
            int cc = i >> 8, r = i & 255, ly = r >> 4, lx = r & 15;
            float v = 0.f;
            if (ly >= 1 && ly <= HP && lx >= 1 && lx <= WP) v = posi[cc*P + (ly-1)*WP + (lx-1)];
            ppad[cc][ly][lx] = v;
        }
        __syncthreads();
        int gid = bid * 256 + tid;
        int c = gid / P, p = gid - c*P, y = p / WP, x2 = p - (p/WP)*WP;
        float v = 0.f;
        #pragma unroll
        for (int ci = 0; ci < POSI; ci++) {
            const float* wr = w0 + (c*POSI + ci)*9;
            v += wr[0]*ppad[ci][y  ][x2] + wr[1]*ppad[ci][y  ][x2+1] + wr[2]*ppad[ci][y  ][x2+2]
               + wr[3]*ppad[ci][y+1][x2] + wr[4]*ppad[ci][y+1][x2+1] + wr[5]*ppad[ci][y+1][x2+2]
               + wr[6]*ppad[ci][y+2][x2] + wr[7]*ppad[ci][y+2][x2+1] + wr[8]*ppad[ci][y+2][x2+2];
        }
        v0[gid] = v;
        float s = v, ss = v * v;
        block_reduce2(s, ss, red, tid, 256);
        if (tid == 0) { pstat[2*bid] = s; pstat[2*bid + 1] = ss; }
    } else if (bid < WF0) {
        // ---- x transpose: x [64][256][196] f32 -> Xt [64][196][256] bf16 ----
        int b2 = bid - XT0;
        int b = b2 >> 3, c0 = (b2 & 7) * 32;
        float* xs = smem;                                        // [32][197]
        for (int i = tid; i < 32 * 49; i += 256) {
            int ci = i / 49, p4 = (i - ci * 49) * 4;
            float4 v = *(const float4*)(x + ((size_t)b * DIMC + c0 + ci) * P + p4);
            float* d = xs + ci * 197 + p4;
            d[0] = v.x; d[1] = v.y; d[2] = v.z; d[3] = v.w;
        }
        __syncthreads();
        for (int j = tid; j < P * 4; j += 256) {
            int pp = j >> 2, c8 = (j & 3) * 8;
            short8 o;
            #pragma unroll
            for (int e = 0; e < 8; e++) o[e] = (short)f2bf(xs[(c8 + e) * 197 + pp]);
            *(short8*)(Xt + ((size_t)b * P + pp) * DIMC + c0 + c8) = o;
        }
    } else if (bid < C0) {
        // ---- wf [12240][576] f32 -> wfb [9][1408][576] bf16 (pad rows zero), 4x ILP ----
        int base = (bid - WF0) * 1024;
        #pragma unroll
        for (int k2 = 0; k2 < 4; k2++) {
            int t = base + k2 * 256 + tid;
            int j = t * 4;
            int rowi = j / KIM, q = j - rowi * KIM;
            int kk = rowi / MW, ch = rowi - kk * MW;
            short4v sv = (short4v)0;
            if (ch < CHN) {
                float4 v = *(const float4*)(wf + ((size_t)(ch * 9 + kk)) * KIM + q);
                sv[0] = (short)f2bf(v.x); sv[1] = (short)f2bf(v.y);
                sv[2] = (short)f2bf(v.z); sv[3] = (short)f2bf(v.w);
            }
            *(short4v*)(wfb + j) = sv;
        }
    } else if (bid < IMZ0) {
        // ---- Win/Wout casts, 4 elements per thread per iter ----
        int base = (bid - C0) * 1024;
        #pragma unroll
        for (int k2 = 0; k2 < 4; k2++) {
            int t = base + k2 * 256 + tid;
            int i0 = t * 4;
            if (i0 < NWIN) {
                short4v sv = (short4v)0;
                if (i0 < CHN * DIMC) {                 // both bounds %4==0: group uniform
                    float4 v = *(const float4*)(Win + i0);
                    sv[0] = (short)f2bf(v.x); sv[1] = (short)f2bf(v.y);
                    sv[2] = (short)f2bf(v.z); sv[3] = (short)f2bf(v.w);
                }
                *(short4v*)(Wbin + i0) = sv;
            } else {
                int j0 = i0 - NWIN;
                int o = j0 / KPAD, k = j0 - o * KPAD;  // KPAD,HID %4==0: group uniform
                short4v sv = (short4v)0;
                if (k < HID) {
                    float4 v = *(const float4*)(Wout + o * HID + k);
                    sv[0] = (short)f2bf(v.x); sv[1] = (short)f2bf(v.y);
                    sv[2] = (short)f2bf(v.z); sv[3] = (short)f2bf(v.w);
                }
                *(short4v*)(Wbout + j0) = sv;
            }
        }
    } else {
        // ---- zero imc (scatter-im2col writes only in-bounds entries) ----
        int base = (bid - IMZ0) * 1024;
        #pragma unroll
        for (int k2 = 0; k2 < 4; k2++) {
            int cc = base + k2 * 256 + tid;
            if (cc < (P * KIM) / 8) *(short8*)(imc + cc * 8) = (short8)0;
        }
    }
}

// ======================= device functions for merged 512-thread launches ================

// convln (512-thread variant): LN(pstat[psi]) + relu folded into staging; conv via LDS w.
__device__ __forceinline__ void dev_convln(char* sm, int bid, int tid,
                                           const float* __restrict__ v_in,
                                           const float* __restrict__ g,
                                           const float* __restrict__ b,
                                           const float* __restrict__ w,
                                           float* __restrict__ v_out,
                                           float* __restrict__ pstat,
                                           int psi, int pso) {
    float* asf = (float*)sm;                 // [64][16][16]
    float* wlf = asf + INTER * 256;          // [3][64][12]
    float* red = wlf + 3 * INTER * 12;       // [16] (8 waves x 2)
    const float inv = 1.f / (float)(INTER * P);
    float s0, ss0;
    sum_pstat(pstat, psi, s0, ss0);
    float mu = s0 * inv;
    float var = ss0 * inv - mu * mu;
    float rstd = rsqrtf(var + EPSLN);

    int gid0 = bid * 256;
    int cA = gid0 / P;                       // block spans c in {cA..cA+2} (256 > P)
    for (int i = tid; i < 3 * INTER * 9; i += 512) {
        int cc = i / (INTER * 9), rest = i - cc * (INTER * 9);
        int ci = rest / 9, kk = rest - ci * 9;
        int crow = cA + cc; if (crow >= INTER) crow = INTER - 1;
        wlf[cc * (INTER * 12) + ci * 12 + kk] = w[(crow * INTER + ci) * 9 + kk];
    }
    for (int i = tid; i < INTER * 64; i += 512)
        *(f32x4*)(asf + i * 4) = (f32x4)0.f;
    __syncthreads();
    #pragma unroll
    for (int it = 0; it < 7; it++) {
        int q4 = it * 512 + tid;
        if (q4 < (INTER * P) / 4) {
            float4 vv = *(const float4*)(v_in + q4 * 4);
            float4 gg = *(const float4*)(g + q4 * 4);
            float4 bb = *(const float4*)(b + q4 * 4);
            float va[4] = {vv.x, vv.y, vv.z, vv.w};
            float ga[4] = {gg.x, gg.y, gg.z, gg.w};
            float ba[4] = {bb.x, bb.y, bb.z, bb.w};
            #pragma unroll
            for (int e = 0; e < 4; e++) {
                int idx = q4 * 4 + e;
                int ci = idx / P, p = idx - ci * P;
                int yy = p / WP, xx = p - yy * WP;
                float a = (va[e] - mu) * rstd * ga[e] + ba[e];
                asf[ci * 256 + (yy + 1) * 16 + (xx + 1)] = a > 0.f ? a : 0.f;
            }
        }
    }
    __syncthreads();
    float s = 0.f, ss = 0.f;
    if (tid < 256) {
        int gid = gid0 + tid;
        int c = gid / P, p = gid - c * P, y = p / WP, x = p - (p / WP) * WP;
        const float* wr0 = wlf + (c - cA) * (INTER * 12);
        float v = 0.f;
        for (int ci = 0; ci < INTER; ci++) {
            const float* wi = wr0 + ci * 12;
            const float* a0 = asf + ci * 256 + y * 16 + x;
            v += wi[0]*a0[0]  + wi[1]*a0[1]  + wi[2]*a0[2]
               + wi[3]*a0[16] + wi[4]*a0[17] + wi[5]*a0[18]
               + wi[6]*a0[32] + wi[7]*a0[33] + wi[8]*a0[34];
        }
        v_out[gid] = v;
        s = v; ss = v * v;
    }
    block_reduce2(s, ss, red, tid, 512);
    if (tid == 0) { pstat[pso + 2*bid] = s; pstat[pso + 2*bid + 1] = ss; }
}

// ln2 + scatter-im2col (no LDS, no barriers -> extra threads may exit)
__device__ __forceinline__ void dev_lnsc(int bid, int tid,
                                         const float* __restrict__ v_in,
                                         const float* __restrict__ g,
                                         const float* __restrict__ b,
                                         const float* __restrict__ pstat,
                                         unsigned short* __restrict__ imc) {
    if (tid >= 256) return;
    const float inv = 1.f / (float)(INTER * P);
    int gid = bid * 256 + tid;
    float s0, ss0;
    sum_pstat(pstat, 196, s0, ss0);
    float mu = s0 * inv;
    float var = ss0 * inv - mu * mu;
    float rstd = rsqrtf(var + EPSLN);
    float a = (v_in[gid] - mu) * rstd * g[gid] + b[gid];
    a = a > 0.f ? a : 0.f;
    unsigned short bv = f2bf(a);
    int ci = gid / P, p = gid - ci * P, y = p / WP, x = p - (p / WP) * WP;
    #pragma unroll
    for (int k = 0; k < 9; k++) {
        int yp = y - (k / 3 - 1), xp = x - (k % 3 - 1);
        if (yp >= 0 && yp < HP && xp >= 0 && xp < WP)
            imc[(yp * WP + xp) * KIM + ci * 9 + k] = bv;
    }
}

// gemm_in 512-thread: 128m x 256n tile, 8 waves each 64x64 (acc[4][4]).  LDS: 48 KB
#define GIN_MT 11
#define GIN_NT 49
#define GIN_BLKS (GIN_MT * GIN_NT)            // 539
__device__ __forceinline__ void dev_gemm_in(char* sm, int mb, int nb, int tid,
                                            const unsigned short* __restrict__ A,
                                            const unsigned short* __restrict__ B,
                                            unsigned short* __restrict__ C) {
    unsigned short* As = (unsigned short*)sm;        // 128*64
    unsigned short* Bs = As + 128 * 64;              // 256*64
    int w = tid >> 6, lane = tid & 63, quad = lane >> 4, c16 = lane & 15;
    int m0 = mb * 128, n0 = nb * 256;
    int wm = (w & 1) * 64, wn = (w >> 1) * 64;       // 2m x 4n wave grid
    f32x4 acc[4][4];
    #pragma unroll
    for (int i = 0; i < 4; i++)
        #pragma unroll
        for (int j = 0; j < 4; j++) acc[i][j] = (f32x4)0.f;

    for (int kc = 0; kc < 4; ++kc) {                 // K=256, chunks of 64
        int k0 = kc * 64;
        if (kc) __syncthreads();
        #pragma unroll
        for (int i = tid; i < 1024; i += 512) {      // A: 128 rows x 8 pieces
            int r = i >> 3, s = i & 7, q = (s - (r >> 1)) & 7;
            gl2lds16(A + (size_t)(m0 + r) * DIMC + k0 + q * 8, As + (i & ~63) * 8);
        }
        #pragma unroll
        for (int i = tid; i < 2048; i += 512) {      // B: 256 rows x 8 pieces
            int r = i >> 3, s = i & 7, q = (s - (r >> 1)) & 7;
            gl2lds16(B + (size_t)(n0 + r) * DIMC + k0 + q * 8, Bs + (i & ~63) * 8);
        }
        __syncthreads();
        #pragma unroll
        for (int ks = 0; ks < 2; ++ks) {
            short8 af[4], bfr[4];
            #pragma unroll
            for (int i = 0; i < 4; i++) af[i] = fragld64(As, wm + i * 16 + c16, ks * 4 + quad);
            #pragma unroll
            for (int j = 0; j < 4; j++) bfr[j] = fragld64(Bs, wn + j * 16 + c16, ks * 4 + quad);
            #pragma unroll
            for (int i = 0; i < 4; i++)
                #pragma unroll
                for (int j = 0; j < 4; j++)
                    acc[i][j] = __builtin_amdgcn_mfma_f32_16x16x32_bf16(af[i], bfr[j], acc[i][j], 0, 0, 0);
        }
    }
    #pragma unroll
    for (int j = 0; j < 4; j++) {
        int n = n0 + wn + j * 16 + c16;
        unsigned short* dst = C + (size_t)n * CHN;
        #pragma unroll
        for (int i = 0; i < 4; i++) {
            int m = m0 + wm + i * 16 + quad * 4;
            if (m < CHN) {
                short4v sv;
                sv[0] = (short)f2bf(acc[i][j][0]);
                sv[1] = (short)f2bf(acc[i][j][1]);
                sv[2] = (short)f2bf(acc[i][j][2]);
                sv[3] = (short)f2bf(acc[i][j][3]);
                *(short4v*)(dst + m) = sv;
            }
        }
    }
}

// gemm_wf 512-thread (bid 0..197): wgtT <- wfb x imc.  LDS: 34.8 KB
__device__ __forceinline__ void dev_gemm_wf(char* sm, int bid, int tid,
                                            const unsigned short* __restrict__ wfb,
                                            const unsigned short* __restrict__ imc,
                                            unsigned short* __restrict__ wgtT) {
    unsigned short* buf = (unsigned short*)sm;       // 64*64 + 208*64
    unsigned short* As = buf;
    unsigned short* Bs = buf + 64 * 64;
    unsigned short* ot = buf;                        // reused after K-loop
    int w = tid >> 6, lane = tid & 63, quad = lane >> 4, c16 = lane & 15;
    int wq = w & 3;
    int f0 = (w < 4) ? 0 : 7;
    int fN = (w < 4) ? 7 : 6;                        // count of f-tiles for this wave
    int m0 = bid * 64;
    int kk = m0 / MW, ch0 = m0 - kk * MW;
    for (int i = tid; i < 96; i += 512)              // zero B pad rows 196..207
        *(short8*)(Bs + 196 * 64 + i * 8) = (short8)0;
    f32x4 acc[7];
    #pragma unroll
    for (int f = 0; f < 7; f++) acc[f] = (f32x4)0.f;

    for (int kc = 0; kc < 9; ++kc) {                 // K=576, chunks of 64
        int k0 = kc * 64;
        if (kc) __syncthreads();
        {
            int i = tid;                             // A: exactly 512 pieces
            int r = i >> 3, s = i & 7, q = (s - (r >> 1)) & 7;
            gl2lds16(wfb + ((size_t)(kk * MW + ch0 + r)) * KIM + k0 + q * 8, As + (i & ~63) * 8);
        }
        for (int i = tid; i < 1568; i += 512) {      // B: 196 rows x 8 pieces
            int r = i >> 3, s = i & 7, q = (s - (r >> 1)) & 7;
            gl2lds16(imc + (size_t)r * KIM + k0 + q * 8, Bs + (i & ~63) * 8);
        }
        __syncthreads();
        #pragma unroll
        for (int ks = 0; ks < 2; ++ks) {
            short8 af = fragld64(As, wq * 16 + c16, ks * 4 + quad);
            #pragma unroll
            for (int f = 0; f < 7; f++) {
                if (f < fN) {
                    short8 bf = fragld64(Bs, (f0 + f) * 16 + c16, ks * 4 + quad);
                    acc[f] = __builtin_amdgcn_mfma_f32_16x16x32_bf16(af, bf, acc[f], 0, 0, 0);
                }
            }
        }
    }
    __syncthreads();
    #pragma unroll
    for (int f = 0; f < 7; f++) {
        if (f < fN) {
            int p = (f0 + f) * 16 + c16;
            if (p < P) {
                short4v sv;
                sv[0] = (short)f2bf(acc[f][0]);
                sv[1] = (short)f2bf(acc[f][1]);
                sv[2] = (short)f2bf(acc[f][2]);
                sv[3] = (short)f2bf(acc[f][3]);
                *(short4v*)(ot + p * 72 + wq * 16 + quad * 4) = sv;
            }
        }
    }
    __syncthreads();
    int nvalid = CHN - ch0; if (nvalid > 64) nvalid = 64;
    for (int p = tid; p < P; p += 512) {
        const short8* src = (const short8*)(ot + p * 72);
        unsigned short* dst = wgtT + ((size_t)p * 9 + kk) * CHN + ch0;
        #pragma unroll
        for (int j = 0; j < 8; j++)
            if (j * 8 < nvalid) *(short8*)(dst + j * 8) = src[j];
    }
}

// ====================== merged 512-thread launches (single occupancy round) ============
#define FA 0
#define FB 161
#define FC 321
#define FD 481
#define CONVLN_LDS ((INTER*256 + 3*INTER*12 + 16) * 4)   // 74816 B (>= gin 49152)
#define GIN_LDS    ((128*64 + 256*64) * 2)               // 49152 B (>= wf 34816)

extern __shared__ char dynsm[];

__global__ __launch_bounds__(512) void k_mA(const float* v0, const float* g0,
                                            const float* b0, const float* w1,
                                            float* v1, float* pstat,
                                            const unsigned short* Wbin,
                                            const unsigned short* Xt,
                                            unsigned short* h1t) {
    int bid = blockIdx.x, tid = threadIdx.x;
    if (bid < 49) dev_convln(dynsm, bid, tid, v0, g0, b0, w1, v1, pstat, 0, 98);
    else { int fid = FA + bid - 49; dev_gemm_in(dynsm, fid % GIN_MT, fid / GIN_MT, tid, Wbin, Xt, h1t); }
}
__global__ __launch_bounds__(512) void k_mB(const float* v1, const float* g1,
                                            const float* b1, const float* w2,
                                            float* v2, float* pstat,
                                            const unsigned short* Wbin,
                                            const unsigned short* Xt,
                                            unsigned short* h1t) {
    int bid = blockIdx.x, tid = threadIdx.x;
    if (bid < 49) dev_convln(dynsm, bid, tid, v1, g1, b1, w2, v2, pstat, 98, 196);
    else { int fid = FB + bid - 49; dev_gemm_in(dynsm, fid % GIN_MT, fid / GIN_MT, tid, Wbin, Xt, h1t); }
}
__global__ __launch_bounds__(512) void k_mC(const float* v2, const float* g2,
                                            const float* b2, const float* pstat,
                                            unsigned short* imc,
                                            const unsigned short* Wbin,
                                            const unsigned short* Xt,
                                            unsigned short* h1t) {
    int bid = blockIdx.x, tid = threadIdx.x;
    if (bid < 49) dev_lnsc(bid, tid, v2, g2, b2, pstat, imc);
    else { int fid = FC + bid - 49; dev_gemm_in(dynsm, fid % GIN_MT, fid / GIN_MT, tid, Wbin, Xt, h1t); }
}
// k_mD: blocks [0,198) = gemm_wf; [198, 198+58) = gemm_in slice
__global__ __launch_bounds__(512) void k_mD(const unsigned short* wfb,
                                            const unsigned short* imc,
                                            unsigned short* wgtT,
                                            const unsigned short* Wbin,
                                            const unsigned short* Xt,
                                            unsigned short* h1t) {
    int bid = blockIdx.x, tid = threadIdx.x;
    if (bid < 198) dev_gemm_wf(dynsm, bid, tid, wfb, imc, wgtT);
    else { int fid = FD + bid - 198; dev_gemm_in(dynsm, fid % GIN_MT, fid / GIN_MT, tid, Wbin, Xt, h1t); }
}

// ============== fused tvconv + gelu-gate + output GEMM (hgt eliminated) ================
// Block = (p, 32-batch group); 512 threads, 8 waves. Per 128-ch chunk: compute gate rows
// into LDS (slot-swizzled, same f2bf values as old hgt), then MFMA vs Wbout (direct L2
// reads). K ascending => accumulation order identical to old k_gemm_out => bit-identical.
__global__ __launch_bounds__(512) void k_tvgo(const unsigned short* __restrict__ h1t,
                                              const unsigned short* __restrict__ wgtT,
                                              const unsigned short* __restrict__ Wbout,
                                              float* __restrict__ out) {
    __shared__ __align__(16) unsigned short wl[9 * CHN];       // 24480 B, [k][CHN]
    __shared__ __align__(16) unsigned short hgbuf[2][32 * 64]; // 8192 B (2 x BK=64 tiles)
    int id = blockIdx.x;
    int xcd = id & 7, q = id >> 3;                 // grid 400: q in [0,50)
    int p = xcd * 25 + (q % 25);
    int bg = q / 25;                               // 0..1 (32 batches each)
    if (p >= P) return;
    int b0 = bg * 32, tid = threadIdx.x;
    int w = tid >> 6, lane = tid & 63, quad = lane >> 4, c16 = lane & 15;
    int wm = w * 32;                               // wave owns m-range [wm, wm+32)

    const unsigned short* wrow = wgtT + (size_t)p * 9 * CHN;
    for (int i = tid * 8; i < 9 * CHN; i += 512 * 8)
        *(short8*)(wl + i) = *(const short8*)(wrow + i);
    int y = p / WP, x = p - (p / WP) * WP;
    int pn[9]; bool pv[9];
    #pragma unroll
    for (int k = 0; k < 9; k++) {
        int yy = y + k / 3 - 1, xx = x + (k % 3) - 1;
        pv[k] = (yy >= 0 && yy < HP && xx >= 0 && xx < WP);
        pn[k] = pv[k] ? yy * WP + xx : 0;
    }
    // gate thread mapping: bl = tid>>4 (batch row 0..31), g = tid&15 (8-ch group in chunk)
    int bl = tid >> 4, g = tid & 15;
    int gs = g >> 3, glp = g & 7;                  // subchunk, logical piece
    unsigned short* hdst = hgbuf[gs] + bl * 64 + (((bl >> 1) + glp) & 7) * 8;
    const unsigned short* hb = h1t + (size_t)(b0 + bl) * P * CHN;

    f32x4 acc[2][2];
    #pragma unroll
    for (int i = 0; i < 2; i++)
        #pragma unroll
        for (int j = 0; j < 2; j++) acc[i][j] = (f32x4)0.f;

    for (int cc = 0; cc < 6; ++cc) {               // K chunks of 128 (last: 64)
        int c0 = cc * 128;
        if (cc) __syncthreads();                   // prev MFMA done before overwrite
        // ---- gate compute: hg[bl][c0+g*8 .. +8] -> LDS (zeros for c >= HID) ----
        {
            int c = c0 + g * 8;
            short8 o = (short8)0;
            if (c < HID) {
                float s1[8], s2[8];
                #pragma unroll
                for (int e = 0; e < 8; e++) { s1[e] = 0.f; s2[e] = 0.f; }
                #pragma unroll
                for (int k = 0; k < 9; k++) {
                    if (!pv[k]) continue;
                    const unsigned short* hr = hb + (size_t)pn[k] * CHN + c;
                    short8 h1v = *(const short8*)hr;
                    short8 h2v = *(const short8*)(hr + HID);
                    short8 w1v = *(const short8*)(wl + k * CHN + c);
                    short8 w2v = *(const short8*)(wl + k * CHN + HID + c);
                    #pragma unroll
                    for (int e = 0; e < 8; e++) {
                        s1[e] += bf2f((unsigned short)w1v[e]) * bf2f((unsigned short)h1v[e]);
                        s2[e] += bf2f((unsigned short)w2v[e]) * bf2f((unsigned short)h2v[e]);
                    }
                }
                #pragma unroll
                for (int e = 0; e < 8; e++) {
                    float gl = 0.5f * s1[e] * (1.f + erff(s1[e] * 0.70710678118654752f));
                    o[e] = (short)f2bf(gl * s2[e]);
                }
            }
            *(short8*)hdst = o;
        }
        __syncthreads();
        // ---- MFMA: A = Wbout rows (direct from L2), B = gate LDS tiles ----
        int nsub = (cc < 5) ? 2 : 1;
        for (int s = 0; s < nsub; ++s) {
            int kbase = c0 + s * 64;
            #pragma unroll
            for (int ks = 0; ks < 2; ++ks) {
                short8 af[2], bfr[2];
                #pragma unroll
                for (int i = 0; i < 2; i++)
                    af[i] = *(const short8*)(Wbout + (size_t)(wm + i * 16 + c16) * KPAD
                                             + kbase + (ks * 4 + quad) * 8);
                #pragma unroll
                for (int j = 0; j < 2; j++)
                    bfr[j] = fragld64(hgbuf[s], j * 16 + c16, ks * 4 + quad);
                #pragma unroll
                for (int i = 0; i < 2; i++)
                    #pragma unroll
                    for (int j = 0; j < 2; j++)
                        acc[i][j] = __builtin_amdgcn_mfma_f32_16x16x32_bf16(af[i], bfr[j], acc[i][j], 0, 0, 0);
            }
        }
    }
    // ---- epilogue: out[(b*DIMC + m)*P + p] ----
    #pragma unroll
    for (int j = 0; j < 2; j++) {
        int b = b0 + j * 16 + c16;
        #pragma unroll
        for (int i = 0; i < 2; i++) {
            int m = wm + i * 16 + quad * 4;
            #pragma unroll
            for (int r = 0; r < 4; r++)
                out[((size_t)b * DIMC + m + r) * P + p] = acc[i][j][r];
        }
    }
}

extern "C" void kernel_launch(void* const* d_in, const int* in_sizes, int n_in,
                              void* d_out, int out_size, void* d_ws, size_t ws_size,
                              hipStream_t stream) {
    (void)in_sizes; (void)n_in; (void)out_size; (void)ws_size;
    const float* x     = (const float*)d_in[0];
    const float* W_in  = (const float*)d_in[1];
    const float* posi  = (const float*)d_in[2];
    const float* w0    = (const float*)d_in[3];
    const float* g0    = (const float*)d_in[4];
    const float* b0    = (const float*)d_in[5];
    const float* w1    = (const float*)d_in[6];
    const float* g1    = (const float*)d_in[7];
    const float* b1    = (const float*)d_in[8];
    const float* w2    = (const float*)d_in[9];
    const float* g2    = (const float*)d_in[10];
    const float* b2    = (const float*)d_in[11];
    const float* wf    = (const float*)d_in[12];
    const float* W_out = (const float*)d_in[13];
    float* out = (float*)d_out;
    char* ws = (char*)d_ws;

    unsigned short* Wbin  = (unsigned short*)(ws + OFS_WBIN);
    unsigned short* Wbout = (unsigned short*)(ws + OFS_WBOUT);
    unsigned short* Xt    = (unsigned short*)(ws + OFS_XT);
    float*          v0    = (float*)(ws + OFS_V0);
    float*          v1    = (float*)(ws + OFS_V1);
    float*          v2    = (float*)(ws + OFS_V2);
    float*          pstat = (float*)(ws + OFS_PST);
    unsigned short* wgtT  = (unsigned short*)(ws + OFS_WGTT);
    unsigned short* h1t   = (unsigned short*)(ws + OFS_H1T);
    unsigned short* imc   = (unsigned short*)(ws + OFS_IMC);
    unsigned short* wfb   = (unsigned short*)(ws + OFS_WFB);

    // 1: fused preamble (conv0 first, then pure streaming branches)
    k_pre<<<PRE_BLKS, 256, 0, stream>>>(
        W_in, W_out, x, wf, posi, w0, Wbin, Wbout, Xt, wfb, imc, v0, pstat);
    // 2-4: wgen stage ∥ gemm_in slice (512-thread blocks, one occupancy round each)
    k_mA<<<49 + (FB - FA), 512, CONVLN_LDS, stream>>>(v0, g0, b0, w1, v1, pstat, Wbin, Xt, h1t);
    k_mB<<<49 + (FC - FB), 512, CONVLN_LDS, stream>>>(v1, g1, b1, w2, v2, pstat, Wbin, Xt, h1t);
    k_mC<<<49 + (FD - FC), 512, CONVLN_LDS, stream>>>(v2, g2, b2, pstat, imc, Wbin, Xt, h1t);
    // 5: gemm_wf ∥ remaining gemm_in blocks
    k_mD<<<198 + (GIN_BLKS - FD), 512, GIN_LDS, stream>>>(wfb, imc, wgtT, Wbin, Xt, h1t);
    // 6: fused tvconv + gate + output GEMM (hgt round-trip eliminated)
    k_tvgo<<<400, 512, 0, stream>>>(h1t, wgtT, Wbout, out);
}

// Round 14
// 212.206 us; speedup vs baseline: 1.0974x; 1.0974x over previous
//
#include <hip/hip_runtime.h>
#include <math.h>

// ---- problem constants ----
#define DIMC   256
#define HID    680
#define CHN    1360
#define HP     14
#define WP     14
#define P      196
#define POSI   4
#define INTER  64
#define BATCH  64
#define KPAD   704          // 680 padded to 22*32
#define OUTCH  12240        // CHN*9
#define MW     1408         // per-k-plane channel pad
#define MTOT   12672        // 9*MW
#define KIM    576          // INTER*9
#define MPADIN 1408         // 1360 padded to 11*128
#define EPSLN  1e-5f

typedef __attribute__((ext_vector_type(8))) short short8;
typedef __attribute__((ext_vector_type(4))) short short4v;
typedef __attribute__((ext_vector_type(4))) float f32x4;

// ---- workspace layout (bytes) ----
#define OFS_WBIN  0u                  // 1408*256*2   = 720896
#define OFS_WBOUT 720896u             // 256*704*2    = 360448
#define OFS_XT    1081344u            // 64*196*256*2 = 6422528
#define OFS_V0    7503872u            // 12544*4
#define OFS_V1    7554048u            // 12544*4
#define OFS_V2    7604224u            // 12544*4
#define OFS_WGTT  7654656u            // 196*9*1360*2 = 4798080
#define OFS_H1T   12452736u           // 64*196*1360*2 = 34127872
#define OFS_HGT   46580608u           // 64*196*704*2  = 17661952
#define OFS_IMC   64242560u           // 196*576*2     = 225792
#define OFS_WFB   64468352u           // 9*1408*576*2  = 14598144
#define OFS_PST   79066496u           // partial LN stats (end ~79.1MB)

__device__ __forceinline__ unsigned short f2bf(float f) {
    union { float f; unsigned u; } v; v.f = f;
    unsigned u = v.u;
    return (unsigned short)((u + 0x7FFFu + ((u >> 16) & 1u)) >> 16);   // RNE
}
__device__ __forceinline__ float bf2f(unsigned short h) {
    union { unsigned u; float f; } v; v.u = ((unsigned)h) << 16; return v.f;
}

// async 16B global->LDS (wave-uniform LDS base + lane*16; global src may be per-lane)
__device__ __forceinline__ void gl2lds16(const unsigned short* g, unsigned short* l) {
    __builtin_amdgcn_global_load_lds(
        (const __attribute__((address_space(1))) unsigned int*)g,
        (__attribute__((address_space(3))) unsigned int*)l, 16, 0, 0);
}
// BK=64 tile: row stride 64, 8 slots of 16B, logical piece lp in 0..7
__device__ __forceinline__ short8 fragld64(const unsigned short* S, int row, int lp) {
    int slot = ((row >> 1) + lp) & 7;
    return *(const short8*)(S + row * 64 + slot * 8);
}

__device__ __forceinline__ void block_reduce2(float& s, float& ss, float* red, int tid, int nthreads) {
    #pragma unroll
    for (int off = 32; off > 0; off >>= 1) {
        s  += __shfl_down(s, off);
        ss += __shfl_down(ss, off);
    }
    int wid = tid >> 6, nw = nthreads >> 6;
    if ((tid & 63) == 0) { red[wid*2] = s; red[wid*2+1] = ss; }
    __syncthreads();
    if (tid == 0) {
        float S = 0.f, SS = 0.f;
        for (int i = 0; i < nw; i++) { S += red[i*2]; SS += red[i*2+1]; }
        red[0] = S; red[1] = SS;
    }
    __syncthreads();
    s = red[0]; ss = red[1];
}

// sum 49 per-block partial (s,ss) pairs — uniform addresses -> scalar loads, unrolled
__device__ __forceinline__ void sum_pstat(const float* __restrict__ pstat, int base,
                                          float& s, float& ss) {
    s = 0.f; ss = 0.f;
    #pragma unroll
    for (int i = 0; i < 49; i++) {
        s  += pstat[base + 2*i];
        ss += pstat[base + 2*i + 1];
    }
}

// ================= fused preamble: conv0 (49 blocks, FIRST) + pure streaming ============
#define NWIN  (MPADIN*DIMC)
#define NWOUT (DIMC*KPAD)
#define XT0   49
#define WF0   561
#define C0    2343
#define IMZ0  2475
#define PRE_BLKS 2489

__global__ __launch_bounds__(256) void k_pre(const float* __restrict__ Win,
                                             const float* __restrict__ Wout,
                                             const float* __restrict__ x,
                                             const float* __restrict__ wf,
                                             const float* __restrict__ posi,
                                             const float* __restrict__ w0,
                                             unsigned short* __restrict__ Wbin,
                                             unsigned short* __restrict__ Wbout,
                                             unsigned short* __restrict__ Xt,
                                             unsigned short* __restrict__ wfb,
                                             unsigned short* __restrict__ imc,
                                             float* __restrict__ v0,
                                             float* __restrict__ pstat) {
    __shared__ __align__(16) float smem[6304];       // 25.2 KB (xt tile / conv0 ppad+red)
    int bid = blockIdx.x, tid = threadIdx.x;
    if (bid < XT0) {
        // ---- conv0: posi (staged padded) * w0 -> v0; partial stats to pstat slots ----
        float (*ppad)[16][16] = (float(*)[16][16])smem;          // 4*256 floats
        float* red = smem + 1024;                                // 16 floats
        for (int i = tid; i < POSI * 256; i += 256) {
            int cc = i >> 8, r = i & 255, ly = r >> 4, lx = r & 15;
            float v = 0.f;
            if (ly >= 1 && ly <= HP && lx >= 1 && lx <= WP) v = posi[cc*P + (ly-1)*WP + (lx-1)];
            ppad[cc][ly][lx] = v;
        }
        __syncthreads();
        int gid = bid * 256 + tid;
        int c = gid / P, p = gid - c*P, y = p / WP, x2 = p - (p/WP)*WP;
        float v = 0.f;
        #pragma unroll
        for (int ci = 0; ci < POSI; ci++) {
            const float* wr = w0 + (c*POSI + ci)*9;
            v += wr[0]*ppad[ci][y  ][x2] + wr[1]*ppad[ci][y  ][x2+1] + wr[2]*ppad[ci][y  ][x2+2]
               + wr[3]*ppad[ci][y+1][x2] + wr[4]*ppad[ci][y+1][x2+1] + wr[5]*ppad[ci][y+1][x2+2]
               + wr[6]*ppad[ci][y+2][x2] + wr[7]*ppad[ci][y+2][x2+1] + wr[8]*ppad[ci][y+2][x2+2];
        }
        v0[gid] = v;
        float s = v, ss = v * v;
        block_reduce2(s, ss, red, tid, 256);
        if (tid == 0) { pstat[2*bid] = s; pstat[2*bid + 1] = ss; }
    } else if (bid < WF0) {
        // ---- x transpose: x [64][256][196] f32 -> Xt [64][196][256] bf16 ----
        int b2 = bid - XT0;
        int b = b2 >> 3, c0 = (b2 & 7) * 32;
        float* xs = smem;                                        // [32][197]
        for (int i = tid; i < 32 * 49; i += 256) {
            int ci = i / 49, p4 = (i - ci * 49) * 4;
            float4 v = *(const float4*)(x + ((size_t)b * DIMC + c0 + ci) * P + p4);
            float* d = xs + ci * 197 + p4;
            d[0] = v.x; d[1] = v.y; d[2] = v.z; d[3] = v.w;
        }
        __syncthreads();
        for (int j = tid; j < P * 4; j += 256) {
            int pp = j >> 2, c8 = (j & 3) * 8;
            short8 o;
            #pragma unroll
            for (int e = 0; e < 8; e++) o[e] = (short)f2bf(xs[(c8 + e) * 197 + pp]);
            *(short8*)(Xt + ((size_t)b * P + pp) * DIMC + c0 + c8) = o;
        }
    } else if (bid < C0) {
        // ---- wf [12240][576] f32 -> wfb [9][1408][576] bf16 (pad rows zero), 4x ILP ----
        int base = (bid - WF0) * 1024;
        #pragma unroll
        for (int k2 = 0; k2 < 4; k2++) {
            int t = base + k2 * 256 + tid;
            int j = t * 4;
            int rowi = j / KIM, q = j - rowi * KIM;
            int kk = rowi / MW, ch = rowi - kk * MW;
            short4v sv = (short4v)0;
            if (ch < CHN) {
                float4 v = *(const float4*)(wf + ((size_t)(ch * 9 + kk)) * KIM + q);
                sv[0] = (short)f2bf(v.x); sv[1] = (short)f2bf(v.y);
                sv[2] = (short)f2bf(v.z); sv[3] = (short)f2bf(v.w);
            }
            *(short4v*)(wfb + j) = sv;
        }
    } else if (bid < IMZ0) {
        // ---- Win/Wout casts, 4 elements per thread per iter ----
        int base = (bid - C0) * 1024;
        #pragma unroll
        for (int k2 = 0; k2 < 4; k2++) {
            int t = base + k2 * 256 + tid;
            int i0 = t * 4;
            if (i0 < NWIN) {
                short4v sv = (short4v)0;
                if (i0 < CHN * DIMC) {                 // both bounds %4==0: group uniform
                    float4 v = *(const float4*)(Win + i0);
                    sv[0] = (short)f2bf(v.x); sv[1] = (short)f2bf(v.y);
                    sv[2] = (short)f2bf(v.z); sv[3] = (short)f2bf(v.w);
                }
                *(short4v*)(Wbin + i0) = sv;
            } else {
                int j0 = i0 - NWIN;
                int o = j0 / KPAD, k = j0 - o * KPAD;  // KPAD,HID %4==0: group uniform
                short4v sv = (short4v)0;
                if (k < HID) {
                    float4 v = *(const float4*)(Wout + o * HID + k);
                    sv[0] = (short)f2bf(v.x); sv[1] = (short)f2bf(v.y);
                    sv[2] = (short)f2bf(v.z); sv[3] = (short)f2bf(v.w);
                }
                *(short4v*)(Wbout + j0) = sv;
            }
        }
    } else {
        // ---- zero imc (scatter-im2col writes only in-bounds entries) ----
        int base = (bid - IMZ0) * 1024;
        #pragma unroll
        for (int k2 = 0; k2 < 4; k2++) {
            int cc = base + k2 * 256 + tid;
            if (cc < (P * KIM) / 8) *(short8*)(imc + cc * 8) = (short8)0;
        }
    }
}

// ======================= device functions for merged 512-thread launches ================

// convln (512-thread variant): LN(pstat[psi]) + relu folded into staging; conv via LDS w.
// All 512 threads hit every barrier; compute guarded to tid<256. LN sums bit-identical
// (extra wave partials are exact zeros; x+0.f==x).
__device__ __forceinline__ void dev_convln(char* sm, int bid, int tid,
                                           const float* __restrict__ v_in,
                                           const float* __restrict__ g,
                                           const float* __restrict__ b,
                                           const float* __restrict__ w,
                                           float* __restrict__ v_out,
                                           float* __restrict__ pstat,
                                           int psi, int pso) {
    float* asf = (float*)sm;                 // [64][16][16]
    float* wlf = asf + INTER * 256;          // [3][64][12]
    float* red = wlf + 3 * INTER * 12;       // [16] (8 waves x 2)
    const float inv = 1.f / (float)(INTER * P);
    float s0, ss0;
    sum_pstat(pstat, psi, s0, ss0);
    float mu = s0 * inv;
    float var = ss0 * inv - mu * mu;
    float rstd = rsqrtf(var + EPSLN);

    int gid0 = bid * 256;
    int cA = gid0 / P;                       // block spans c in {cA..cA+2} (256 > P)
    for (int i = tid; i < 3 * INTER * 9; i += 512) {
        int cc = i / (INTER * 9), rest = i - cc * (INTER * 9);
        int ci = rest / 9, kk = rest - ci * 9;
        int crow = cA + cc; if (crow >= INTER) crow = INTER - 1;
        wlf[cc * (INTER * 12) + ci * 12 + kk] = w[(crow * INTER + ci) * 9 + kk];
    }
    for (int i = tid; i < INTER * 64; i += 512)
        *(f32x4*)(asf + i * 4) = (f32x4)0.f;
    __syncthreads();
    #pragma unroll
    for (int it = 0; it < 7; it++) {
        int q4 = it * 512 + tid;
        if (q4 < (INTER * P) / 4) {
            float4 vv = *(const float4*)(v_in + q4 * 4);
            float4 gg = *(const float4*)(g + q4 * 4);
            float4 bb = *(const float4*)(b + q4 * 4);
            float va[4] = {vv.x, vv.y, vv.z, vv.w};
            float ga[4] = {gg.x, gg.y, gg.z, gg.w};
            float ba[4] = {bb.x, bb.y, bb.z, bb.w};
            #pragma unroll
            for (int e = 0; e < 4; e++) {
                int idx = q4 * 4 + e;
                int ci = idx / P, p = idx - ci * P;
                int yy = p / WP, xx = p - yy * WP;
                float a = (va[e] - mu) * rstd * ga[e] + ba[e];
                asf[ci * 256 + (yy + 1) * 16 + (xx + 1)] = a > 0.f ? a : 0.f;
            }
        }
    }
    __syncthreads();
    float s = 0.f, ss = 0.f;
    if (tid < 256) {
        int gid = gid0 + tid;
        int c = gid / P, p = gid - c * P, y = p / WP, x = p - (p / WP) * WP;
        const float* wr0 = wlf + (c - cA) * (INTER * 12);
        float v = 0.f;
        for (int ci = 0; ci < INTER; ci++) {
            const float* wi = wr0 + ci * 12;
            const float* a0 = asf + ci * 256 + y * 16 + x;
            v += wi[0]*a0[0]  + wi[1]*a0[1]  + wi[2]*a0[2]
               + wi[3]*a0[16] + wi[4]*a0[17] + wi[5]*a0[18]
               + wi[6]*a0[32] + wi[7]*a0[33] + wi[8]*a0[34];
        }
        v_out[gid] = v;
        s = v; ss = v * v;
    }
    block_reduce2(s, ss, red, tid, 512);
    if (tid == 0) { pstat[pso + 2*bid] = s; pstat[pso + 2*bid + 1] = ss; }
}

// ln2 + scatter-im2col (no LDS, no barriers -> extra threads may exit)
__device__ __forceinline__ void dev_lnsc(int bid, int tid,
                                         const float* __restrict__ v_in,
                                         const float* __restrict__ g,
                                         const float* __restrict__ b,
                                         const float* __restrict__ pstat,
                                         unsigned short* __restrict__ imc) {
    if (tid >= 256) return;
    const float inv = 1.f / (float)(INTER * P);
    int gid = bid * 256 + tid;
    float s0, ss0;
    sum_pstat(pstat, 196, s0, ss0);
    float mu = s0 * inv;
    float var = ss0 * inv - mu * mu;
    float rstd = rsqrtf(var + EPSLN);
    float a = (v_in[gid] - mu) * rstd * g[gid] + b[gid];
    a = a > 0.f ? a : 0.f;
    unsigned short bv = f2bf(a);
    int ci = gid / P, p = gid - ci * P, y = p / WP, x = p - (p / WP) * WP;
    #pragma unroll
    for (int k = 0; k < 9; k++) {
        int yp = y - (k / 3 - 1), xp = x - (k % 3 - 1);
        if (yp >= 0 && yp < HP && xp >= 0 && xp < WP)
            imc[(yp * WP + xp) * KIM + ci * 9 + k] = bv;
    }
}

// gemm_in 512-thread: 128m x 256n tile, 8 waves each 64x64 (acc[4][4]).  LDS: 48 KB
#define GIN_MT 11
#define GIN_NT 49
#define GIN_BLKS (GIN_MT * GIN_NT)            // 539
__device__ __forceinline__ void dev_gemm_in(char* sm, int mb, int nb, int tid,
                                            const unsigned short* __restrict__ A,
                                            const unsigned short* __restrict__ B,
                                            unsigned short* __restrict__ C) {
    unsigned short* As = (unsigned short*)sm;        // 128*64
    unsigned short* Bs = As + 128 * 64;              // 256*64
    int w = tid >> 6, lane = tid & 63, quad = lane >> 4, c16 = lane & 15;
    int m0 = mb * 128, n0 = nb * 256;
    int wm = (w & 1) * 64, wn = (w >> 1) * 64;       // 2m x 4n wave grid
    f32x4 acc[4][4];
    #pragma unroll
    for (int i = 0; i < 4; i++)
        #pragma unroll
        for (int j = 0; j < 4; j++) acc[i][j] = (f32x4)0.f;

    for (int kc = 0; kc < 4; ++kc) {                 // K=256, chunks of 64
        int k0 = kc * 64;
        if (kc) __syncthreads();
        #pragma unroll
        for (int i = tid; i < 1024; i += 512) {      // A: 128 rows x 8 pieces
            int r = i >> 3, s = i & 7, q = (s - (r >> 1)) & 7;
            gl2lds16(A + (size_t)(m0 + r) * DIMC + k0 + q * 8, As + (i & ~63) * 8);
        }
        #pragma unroll
        for (int i = tid; i < 2048; i += 512) {      // B: 256 rows x 8 pieces
            int r = i >> 3, s = i & 7, q = (s - (r >> 1)) & 7;
            gl2lds16(B + (size_t)(n0 + r) * DIMC + k0 + q * 8, Bs + (i & ~63) * 8);
        }
        __syncthreads();
        #pragma unroll
        for (int ks = 0; ks < 2; ++ks) {
            short8 af[4], bfr[4];
            #pragma unroll
            for (int i = 0; i < 4; i++) af[i] = fragld64(As, wm + i * 16 + c16, ks * 4 + quad);
            #pragma unroll
            for (int j = 0; j < 4; j++) bfr[j] = fragld64(Bs, wn + j * 16 + c16, ks * 4 + quad);
            #pragma unroll
            for (int i = 0; i < 4; i++)
                #pragma unroll
                for (int j = 0; j < 4; j++)
                    acc[i][j] = __builtin_amdgcn_mfma_f32_16x16x32_bf16(af[i], bfr[j], acc[i][j], 0, 0, 0);
        }
    }
    #pragma unroll
    for (int j = 0; j < 4; j++) {
        int n = n0 + wn + j * 16 + c16;
        unsigned short* dst = C + (size_t)n * CHN;
        #pragma unroll
        for (int i = 0; i < 4; i++) {
            int m = m0 + wm + i * 16 + quad * 4;
            if (m < CHN) {
                short4v sv;
                sv[0] = (short)f2bf(acc[i][j][0]);
                sv[1] = (short)f2bf(acc[i][j][1]);
                sv[2] = (short)f2bf(acc[i][j][2]);
                sv[3] = (short)f2bf(acc[i][j][3]);
                *(short4v*)(dst + m) = sv;
            }
        }
    }
}

// gemm_wf 512-thread (bid 0..197): wgtT <- wfb x imc.  LDS: 34.8 KB
// 8 waves: waves 0-3 handle f 0..6, waves 4-7 handle f 7..12, m-col = (w&3)*16.
__device__ __forceinline__ void dev_gemm_wf(char* sm, int bid, int tid,
                                            const unsigned short* __restrict__ wfb,
                                            const unsigned short* __restrict__ imc,
                                            unsigned short* __restrict__ wgtT) {
    unsigned short* buf = (unsigned short*)sm;       // 64*64 + 208*64
    unsigned short* As = buf;
    unsigned short* Bs = buf + 64 * 64;
    unsigned short* ot = buf;                        // reused after K-loop
    int w = tid >> 6, lane = tid & 63, quad = lane >> 4, c16 = lane & 15;
    int wq = w & 3;
    int f0 = (w < 4) ? 0 : 7;
    int fN = (w < 4) ? 7 : 6;                        // count of f-tiles for this wave
    int m0 = bid * 64;
    int kk = m0 / MW, ch0 = m0 - kk * MW;
    for (int i = tid; i < 96; i += 512)              // zero B pad rows 196..207
        *(short8*)(Bs + 196 * 64 + i * 8) = (short8)0;
    f32x4 acc[7];
    #pragma unroll
    for (int f = 0; f < 7; f++) acc[f] = (f32x4)0.f;

    for (int kc = 0; kc < 9; ++kc) {                 // K=576, chunks of 64
        int k0 = kc * 64;
        if (kc) __syncthreads();
        {
            int i = tid;                             // A: exactly 512 pieces
            int r = i >> 3, s = i & 7, q = (s - (r >> 1)) & 7;
            gl2lds16(wfb + ((size_t)(kk * MW + ch0 + r)) * KIM + k0 + q * 8, As + (i & ~63) * 8);
        }
        for (int i = tid; i < 1568; i += 512) {      // B: 196 rows x 8 pieces
            int r = i >> 3, s = i & 7, q = (s - (r >> 1)) & 7;
            gl2lds16(imc + (size_t)r * KIM + k0 + q * 8, Bs + (i & ~63) * 8);
        }
        __syncthreads();
        #pragma unroll
        for (int ks = 0; ks < 2; ++ks) {
            short8 af = fragld64(As, wq * 16 + c16, ks * 4 + quad);
            #pragma unroll
            for (int f = 0; f < 7; f++) {
                if (f < fN) {
                    short8 bf = fragld64(Bs, (f0 + f) * 16 + c16, ks * 4 + quad);
                    acc[f] = __builtin_amdgcn_mfma_f32_16x16x32_bf16(af, bf, acc[f], 0, 0, 0);
                }
            }
        }
    }
    __syncthreads();
    #pragma unroll
    for (int f = 0; f < 7; f++) {
        if (f < fN) {
            int p = (f0 + f) * 16 + c16;
            if (p < P) {
                short4v sv;
                sv[0] = (short)f2bf(acc[f][0]);
                sv[1] = (short)f2bf(acc[f][1]);
                sv[2] = (short)f2bf(acc[f][2]);
                sv[3] = (short)f2bf(acc[f][3]);
                *(short4v*)(ot + p * 72 + wq * 16 + quad * 4) = sv;
            }
        }
    }
    __syncthreads();
    int nvalid = CHN - ch0; if (nvalid > 64) nvalid = 64;
    for (int p = tid; p < P; p += 512) {
        const short8* src = (const short8*)(ot + p * 72);
        unsigned short* dst = wgtT + ((size_t)p * 9 + kk) * CHN + ch0;
        #pragma unroll
        for (int j = 0; j < 8; j++)
            if (j * 8 < nvalid) *(short8*)(dst + j * 8) = src[j];
    }
}

// ====================== merged 512-thread launches (single occupancy round) ============
// gemm_in fid bases: mA [0,161), mB [161,321), mC [321,481), mD [481,539)
#define FA 0
#define FB 161
#define FC 321
#define FD 481
#define CONVLN_LDS ((INTER*256 + 3*INTER*12 + 16) * 4)   // 74816 B (>= gin 49152)
#define GIN_LDS    ((128*64 + 256*64) * 2)               // 49152 B (>= wf 34816)

extern __shared__ char dynsm[];

__global__ __launch_bounds__(512) void k_mA(const float* v0, const float* g0,
                                            const float* b0, const float* w1,
                                            float* v1, float* pstat,
                                            const unsigned short* Wbin,
                                            const unsigned short* Xt,
                                            unsigned short* h1t) {
    int bid = blockIdx.x, tid = threadIdx.x;
    if (bid < 49) dev_convln(dynsm, bid, tid, v0, g0, b0, w1, v1, pstat, 0, 98);
    else { int fid = FA + bid - 49; dev_gemm_in(dynsm, fid % GIN_MT, fid / GIN_MT, tid, Wbin, Xt, h1t); }
}
__global__ __launch_bounds__(512) void k_mB(const float* v1, const float* g1,
                                            const float* b1, const float* w2,
                                            float* v2, float* pstat,
                                            const unsigned short* Wbin,
                                            const unsigned short* Xt,
                                            unsigned short* h1t) {
    int bid = blockIdx.x, tid = threadIdx.x;
    if (bid < 49) dev_convln(dynsm, bid, tid, v1, g1, b1, w2, v2, pstat, 98, 196);
    else { int fid = FB + bid - 49; dev_gemm_in(dynsm, fid % GIN_MT, fid / GIN_MT, tid, Wbin, Xt, h1t); }
}
__global__ __launch_bounds__(512) void k_mC(const float* v2, const float* g2,
                                            const float* b2, const float* pstat,
                                            unsigned short* imc,
                                            const unsigned short* Wbin,
                                            const unsigned short* Xt,
                                            unsigned short* h1t) {
    int bid = blockIdx.x, tid = threadIdx.x;
    if (bid < 49) dev_lnsc(bid, tid, v2, g2, b2, pstat, imc);
    else { int fid = FC + bid - 49; dev_gemm_in(dynsm, fid % GIN_MT, fid / GIN_MT, tid, Wbin, Xt, h1t); }
}
// k_mD: blocks [0,198) = gemm_wf; [198, 198+58) = gemm_in slice
__global__ __launch_bounds__(512) void k_mD(const unsigned short* wfb,
                                            const unsigned short* imc,
                                            unsigned short* wgtT,
                                            const unsigned short* Wbin,
                                            const unsigned short* Xt,
                                            unsigned short* h1t) {
    int bid = blockIdx.x, tid = threadIdx.x;
    if (bid < 198) dev_gemm_wf(dynsm, bid, tid, wfb, imc, wgtT);
    else { int fid = FD + bid - 198; dev_gemm_in(dynsm, fid % GIN_MT, fid / GIN_MT, tid, Wbin, Xt, h1t); }
}

// -------- fused tvconv + gelu-gate: 512 threads, 16 batches/block, XCD swizzle ---------
__global__ __launch_bounds__(512) void k_tvg(const unsigned short* __restrict__ h1t,
                                             const unsigned short* __restrict__ wgtT,
                                             unsigned short* __restrict__ hgt) {
    __shared__ __align__(16) unsigned short wl[9 * CHN];   // 24480 B, [k][CHN]
    int id = blockIdx.x;
    int xcd = id & 7, q = id >> 3;                         // grid 800: q in [0,100)
    int p = xcd * 25 + (q % 25);
    int bg = q / 25;                                       // 0..3 (16 batches each)
    if (p >= P) return;
    int b0 = bg * 16, tid = threadIdx.x;
    const unsigned short* wrow = wgtT + (size_t)p * 9 * CHN;
    for (int i = tid * 8; i < 9 * CHN; i += 512 * 8)
        *(short8*)(wl + i) = *(const short8*)(wrow + i);
    int y = p / WP, x = p - (p / WP) * WP;
    int pn[9]; bool pv[9];
    #pragma unroll
    for (int k = 0; k < 9; k++) {
        int yy = y + k / 3 - 1, xx = x + (k % 3) - 1;
        pv[k] = (yy >= 0 && yy < HP && xx >= 0 && xx < WP);
        pn[k] = pv[k] ? yy * WP + xx : 0;
    }
    __syncthreads();
    for (int j = tid; j < 16 * 85; j += 512) {
        int bl = j / 85, c = (j - bl * 85) * 8;
        int b = b0 + bl;
        const unsigned short* hb = h1t + (size_t)b * P * CHN;
        float s1[8], s2[8];
        #pragma unroll
        for (int e = 0; e < 8; e++) { s1[e] = 0.f; s2[e] = 0.f; }
        #pragma unroll
        for (int k = 0; k < 9; k++) {
            if (!pv[k]) continue;
            const unsigned short* hr = hb + (size_t)pn[k] * CHN + c;
            short8 h1v = *(const short8*)hr;
            short8 h2v = *(const short8*)(hr + HID);
            short8 w1v = *(const short8*)(wl + k * CHN + c);
            short8 w2v = *(const short8*)(wl + k * CHN + HID + c);
            #pragma unroll
            for (int e = 0; e < 8; e++) {
                s1[e] += bf2f((unsigned short)w1v[e]) * bf2f((unsigned short)h1v[e]);
                s2[e] += bf2f((unsigned short)w2v[e]) * bf2f((unsigned short)h2v[e]);
            }
        }
        short8 o;
        #pragma unroll
        for (int e = 0; e < 8; e++) {
            float gl = 0.5f * s1[e] * (1.f + erff(s1[e] * 0.70710678118654752f));
            o[e] = (short)f2bf(gl * s2[e]);
        }
        *(short8*)(hgt + ((size_t)b * P + p) * KPAD + c) = o;
    }
    if (tid < 48) {
        int bl = tid / 3, z = (tid - bl * 3) * 8;
        *(short8*)(hgt + ((size_t)(b0 + bl) * P + p) * KPAD + HID + z) = (short8)0;
    }
}

// ---------------- tiled MFMA GEMM 2 (BK=64): out[m][n] = sum_k Wbout[m][k] hgt[n][k] ------
__global__ __launch_bounds__(256) void k_gemm_out(const unsigned short* __restrict__ A,
                                                  const unsigned short* __restrict__ B,
                                                  float* __restrict__ out) {
    __shared__ __align__(16) unsigned short As[64 * 64];     // 8 KB
    __shared__ __align__(16) unsigned short Bs[128 * 64];    // 16 KB
    int tid = threadIdx.x;
    int w = tid >> 6, lane = tid & 63, quad = lane >> 4, c16 = lane & 15;
    int m0 = blockIdx.x * 64, n0 = blockIdx.y * 128;
    int wm = (w & 1) * 32, wn = (w >> 1) * 64;
    f32x4 acc[2][4];
    #pragma unroll
    for (int i = 0; i < 2; i++)
        #pragma unroll
        for (int j = 0; j < 4; j++) acc[i][j] = (f32x4)0.f;

    for (int kc = 0; kc < 11; ++kc) {                        // K=704, chunks of 64
        int k0 = kc * 64;
        if (kc) __syncthreads();
        #pragma unroll
        for (int i = tid; i < 512; i += 256) {               // A: 64 rows x 8 pieces
            int r = i >> 3, s = i & 7, q = (s - (r >> 1)) & 7;
            gl2lds16(A + (size_t)(m0 + r) * KPAD + k0 + q * 8, As + (i & ~63) * 8);
        }
        #pragma unroll
        for (int i = tid; i < 1024; i += 256) {              // B: 128 rows x 8 pieces
            int r = i >> 3, s = i & 7, q = (s - (r >> 1)) & 7;
            gl2lds16(B + (size_t)(n0 + r) * KPAD + k0 + q * 8, Bs + (i & ~63) * 8);
        }
        __syncthreads();
        #pragma unroll
        for (int ks = 0; ks < 2; ++ks) {
            short8 af[2], bfr[4];
            #pragma unroll
            for (int i = 0; i < 2; i++) af[i] = fragld64(As, wm + i * 16 + c16, ks * 4 + quad);
            #pragma unroll
            for (int j = 0; j < 4; j++) bfr[j] = fragld64(Bs, wn + j * 16 + c16, ks * 4 + quad);
            #pragma unroll
            for (int i = 0; i < 2; i++)
                #pragma unroll
                for (int j = 0; j < 4; j++)
                    acc[i][j] = __builtin_amdgcn_mfma_f32_16x16x32_bf16(af[i], bfr[j], acc[i][j], 0, 0, 0);
        }
    }
    #pragma unroll
    for (int j = 0; j < 4; j++) {
        int n = n0 + wn + j * 16 + c16;
        int b = n / P, pp = n - b * P;
        #pragma unroll
        for (int i = 0; i < 2; i++) {
            int m = m0 + wm + i * 16 + quad * 4;
            #pragma unroll
            for (int r = 0; r < 4; r++)
                out[((size_t)b * DIMC + m + r) * P + pp] = acc[i][j][r];
        }
    }
}

extern "C" void kernel_launch(void* const* d_in, const int* in_sizes, int n_in,
                              void* d_out, int out_size, void* d_ws, size_t ws_size,
                              hipStream_t stream) {
    (void)in_sizes; (void)n_in; (void)out_size; (void)ws_size;
    const float* x     = (const float*)d_in[0];
    const float* W_in  = (const float*)d_in[1];
    const float* posi  = (const float*)d_in[2];
    const float* w0    = (const float*)d_in[3];
    const float* g0    = (const float*)d_in[4];
    const float* b0    = (const float*)d_in[5];
    const float* w1    = (const float*)d_in[6];
    const float* g1    = (const float*)d_in[7];
    const float* b1    = (const float*)d_in[8];
    const float* w2    = (const float*)d_in[9];
    const float* g2    = (const float*)d_in[10];
    const float* b2    = (const float*)d_in[11];
    const float* wf    = (const float*)d_in[12];
    const float* W_out = (const float*)d_in[13];
    float* out = (float*)d_out;
    char* ws = (char*)d_ws;

    unsigned short* Wbin  = (unsigned short*)(ws + OFS_WBIN);
    unsigned short* Wbout = (unsigned short*)(ws + OFS_WBOUT);
    unsigned short* Xt    = (unsigned short*)(ws + OFS_XT);
    float*          v0    = (float*)(ws + OFS_V0);
    float*          v1    = (float*)(ws + OFS_V1);
    float*          v2    = (float*)(ws + OFS_V2);
    float*          pstat = (float*)(ws + OFS_PST);
    unsigned short* wgtT  = (unsigned short*)(ws + OFS_WGTT);
    unsigned short* h1t   = (unsigned short*)(ws + OFS_H1T);
    unsigned short* hgt   = (unsigned short*)(ws + OFS_HGT);
    unsigned short* imc   = (unsigned short*)(ws + OFS_IMC);
    unsigned short* wfb   = (unsigned short*)(ws + OFS_WFB);

    // 1: fused preamble (conv0 first, then pure streaming branches)
    k_pre<<<PRE_BLKS, 256, 0, stream>>>(
        W_in, W_out, x, wf, posi, w0, Wbin, Wbout, Xt, wfb, imc, v0, pstat);
    // 2-4: wgen stage ∥ gemm_in slice (512-thread blocks, one occupancy round each)
    k_mA<<<49 + (FB - FA), 512, CONVLN_LDS, stream>>>(v0, g0, b0, w1, v1, pstat, Wbin, Xt, h1t);
    k_mB<<<49 + (FC - FB), 512, CONVLN_LDS, stream>>>(v1, g1, b1, w2, v2, pstat, Wbin, Xt, h1t);
    k_mC<<<49 + (FD - FC), 512, CONVLN_LDS, stream>>>(v2, g2, b2, pstat, imc, Wbin, Xt, h1t);
    // 5: gemm_wf ∥ remaining gemm_in blocks
    k_mD<<<198 + (GIN_BLKS - FD), 512, GIN_LDS, stream>>>(wfb, imc, wgtT, Wbin, Xt, h1t);
    // 6-7: tvconv+gate (512 threads, 16 batches/block), output GEMM
    k_tvg     <<<800, 512, 0, stream>>>(h1t, wgtT, hgt);
    k_gemm_out<<<dim3(DIMC/64, (BATCH*P)/128), 256, 0, stream>>>(Wbout, hgt, out);
}

// Round 15
// 209.614 us; speedup vs baseline: 1.1110x; 1.0124x over previous
//
#include <hip/hip_runtime.h>
#include <math.h>

// ---- problem constants ----
#define DIMC   256
#define HID    680
#define CHN    1360
#define HP     14
#define WP     14
#define P      196
#define POSI   4
#define INTER  64
#define BATCH  64
#define KPAD   704          // 680 padded to 22*32
#define OUTCH  12240        // CHN*9
#define MW     1408         // per-k-plane channel pad
#define MTOT   12672        // 9*MW
#define KIM    576          // INTER*9
#define MPADIN 1408         // 1360 padded to 11*128
#define EPSLN  1e-5f

typedef __attribute__((ext_vector_type(8))) short short8;
typedef __attribute__((ext_vector_type(4))) short short4v;
typedef __attribute__((ext_vector_type(4))) float f32x4;

// ---- workspace layout (bytes) ----
#define OFS_WBIN  0u                  // 1408*256*2   = 720896
#define OFS_WBOUT 720896u             // 256*704*2    = 360448
#define OFS_XT    1081344u            // 64*196*256*2 = 6422528
#define OFS_V0    7503872u            // 12544*4
#define OFS_V1    7554048u            // 12544*4
#define OFS_V2    7604224u            // 12544*4
#define OFS_WGTT  7654656u            // 196*9*1360*2 = 4798080
#define OFS_H1T   12452736u           // 64*196*1360*2 = 34127872
#define OFS_HGT   46580608u           // 64*196*704*2  = 17661952
#define OFS_IMC   64242560u           // 196*576*2     = 225792
#define OFS_WFB   64468352u           // 9*1408*576*2  = 14598144
#define OFS_PST   79066496u           // partial LN stats (end ~79.1MB)

__device__ __forceinline__ unsigned short f2bf(float f) {
    union { float f; unsigned u; } v; v.f = f;
    unsigned u = v.u;
    return (unsigned short)((u + 0x7FFFu + ((u >> 16) & 1u)) >> 16);   // RNE
}
__device__ __forceinline__ float bf2f(unsigned short h) {
    union { unsigned u; float f; } v; v.u = ((unsigned)h) << 16; return v.f;
}

// async 16B global->LDS (wave-uniform LDS base + lane*16; global src may be per-lane)
__device__ __forceinline__ void gl2lds16(const unsigned short* g, unsigned short* l) {
    __builtin_amdgcn_global_load_lds(
        (const __attribute__((address_space(1))) unsigned int*)g,
        (__attribute__((address_space(3))) unsigned int*)l, 16, 0, 0);
}
// BK=64 tile: row stride 64, 8 slots of 16B, logical piece lp in 0..7
__device__ __forceinline__ short8 fragld64(const unsigned short* S, int row, int lp) {
    int slot = ((row >> 1) + lp) & 7;
    return *(const short8*)(S + row * 64 + slot * 8);
}

__device__ __forceinline__ void block_reduce2(float& s, float& ss, float* red, int tid, int nthreads) {
    #pragma unroll
    for (int off = 32; off > 0; off >>= 1) {
        s  += __shfl_down(s, off);
        ss += __shfl_down(ss, off);
    }
    int wid = tid >> 6, nw = nthreads >> 6;
    if ((tid & 63) == 0) { red[wid*2] = s; red[wid*2+1] = ss; }
    __syncthreads();
    if (tid == 0) {
        float S = 0.f, SS = 0.f;
        for (int i = 0; i < nw; i++) { S += red[i*2]; SS += red[i*2+1]; }
        red[0] = S; red[1] = SS;
    }
    __syncthreads();
    s = red[0]; ss = red[1];
}

// sum 49 per-block partial (s,ss) pairs — uniform addresses -> scalar loads, unrolled
__device__ __forceinline__ void sum_pstat(const float* __restrict__ pstat, int base,
                                          float& s, float& ss) {
    s = 0.f; ss = 0.f;
    #pragma unroll
    for (int i = 0; i < 49; i++) {
        s  += pstat[base + 2*i];
        ss += pstat[base + 2*i + 1];
    }
}

// ====== preamble (SLIM): conv0 (49) + x transpose (512) + Win cast (88) = 649 blocks ===
// wf cast / Wout cast / imc zero moved into k_mA as filler (consumed only by mC/mD/out).
#define NWIN  (MPADIN*DIMC)
#define NWOUT (DIMC*KPAD)
#define XT0   49
#define WC0   561
#define PRE_BLKS 649

__global__ __launch_bounds__(256) void k_pre(const float* __restrict__ Win,
                                             const float* __restrict__ x,
                                             const float* __restrict__ posi,
                                             const float* __restrict__ w0,
                                             unsigned short* __restrict__ Wbin,
                                             unsigned short* __restrict__ Xt,
                                             float* __restrict__ v0,
                                             float* __restrict__ pstat) {
    __shared__ __align__(16) float smem[6304];       // 25.2 KB (xt tile / conv0 ppad+red)
    int bid = blockIdx.x, tid = threadIdx.x;
    if (bid < XT0) {
        // ---- conv0: posi (staged padded) * w0 -> v0; partial stats to pstat slots ----
        float (*ppad)[16][16] = (float(*)[16][16])smem;          // 4*256 floats
        float* red = smem + 1024;                                // 16 floats
        for (int i = tid; i < POSI * 256; i += 256) {
            int cc = i >> 8, r = i & 255, ly = r >> 4, lx = r & 15;
            float v = 0.f;
            if (ly >= 1 && ly <= HP && lx >= 1 && lx <= WP) v = posi[cc*P + (ly-1)*WP + (lx-1)];
            ppad[cc][ly][lx] = v;
        }
        __syncthreads();
        int gid = bid * 256 + tid;
        int c = gid / P, p = gid - c*P, y = p / WP, x2 = p - (p/WP)*WP;
        float v = 0.f;
        #pragma unroll
        for (int ci = 0; ci < POSI; ci++) {
            const float* wr = w0 + (c*POSI + ci)*9;
            v += wr[0]*ppad[ci][y  ][x2] + wr[1]*ppad[ci][y  ][x2+1] + wr[2]*ppad[ci][y  ][x2+2]
               + wr[3]*ppad[ci][y+1][x2] + wr[4]*ppad[ci][y+1][x2+1] + wr[5]*ppad[ci][y+1][x2+2]
               + wr[6]*ppad[ci][y+2][x2] + wr[7]*ppad[ci][y+2][x2+1] + wr[8]*ppad[ci][y+2][x2+2];
        }
        v0[gid] = v;
        float s = v, ss = v * v;
        block_reduce2(s, ss, red, tid, 256);
        if (tid == 0) { pstat[2*bid] = s; pstat[2*bid + 1] = ss; }
    } else if (bid < WC0) {
        // ---- x transpose: x [64][256][196] f32 -> Xt [64][196][256] bf16 ----
        int b2 = bid - XT0;
        int b = b2 >> 3, c0 = (b2 & 7) * 32;
        float* xs = smem;                                        // [32][197]
        for (int i = tid; i < 32 * 49; i += 256) {
            int ci = i / 49, p4 = (i - ci * 49) * 4;
            float4 v = *(const float4*)(x + ((size_t)b * DIMC + c0 + ci) * P + p4);
            float* d = xs + ci * 197 + p4;
            d[0] = v.x; d[1] = v.y; d[2] = v.z; d[3] = v.w;
        }
        __syncthreads();
        for (int j = tid; j < P * 4; j += 256) {
            int pp = j >> 2, c8 = (j & 3) * 8;
            short8 o;
            #pragma unroll
            for (int e = 0; e < 8; e++) o[e] = (short)f2bf(xs[(c8 + e) * 197 + pp]);
            *(short8*)(Xt + ((size_t)b * P + pp) * DIMC + c0 + c8) = o;
        }
    } else {
        // ---- Win cast (incl. pad rows), 88 blocks x 4096 elems = NWIN exactly ----
        int base = (bid - WC0) * 1024;
        #pragma unroll
        for (int k2 = 0; k2 < 4; k2++) {
            int t = base + k2 * 256 + tid;
            int i0 = t * 4;
            short4v sv = (short4v)0;
            if (i0 < CHN * DIMC) {                 // bound %4==0: group uniform
                float4 v = *(const float4*)(Win + i0);
                sv[0] = (short)f2bf(v.x); sv[1] = (short)f2bf(v.y);
                sv[2] = (short)f2bf(v.z); sv[3] = (short)f2bf(v.w);
            }
            *(short4v*)(Wbin + i0) = sv;
        }
    }
}

// ======================= device functions for merged 512-thread launches ================

// convln (512-thread variant): LN(pstat[psi]) + relu folded into staging; conv via LDS w.
__device__ __forceinline__ void dev_convln(char* sm, int bid, int tid,
                                           const float* __restrict__ v_in,
                                           const float* __restrict__ g,
                                           const float* __restrict__ b,
                                           const float* __restrict__ w,
                                           float* __restrict__ v_out,
                                           float* __restrict__ pstat,
                                           int psi, int pso) {
    float* asf = (float*)sm;                 // [64][16][16]
    float* wlf = asf + INTER * 256;          // [3][64][12]
    float* red = wlf + 3 * INTER * 12;       // [16] (8 waves x 2)
    const float inv = 1.f / (float)(INTER * P);
    float s0, ss0;
    sum_pstat(pstat, psi, s0, ss0);
    float mu = s0 * inv;
    float var = ss0 * inv - mu * mu;
    float rstd = rsqrtf(var + EPSLN);

    int gid0 = bid * 256;
    int cA = gid0 / P;                       // block spans c in {cA..cA+2} (256 > P)
    for (int i = tid; i < 3 * INTER * 9; i += 512) {
        int cc = i / (INTER * 9), rest = i - cc * (INTER * 9);
        int ci = rest / 9, kk = rest - ci * 9;
        int crow = cA + cc; if (crow >= INTER) crow = INTER - 1;
        wlf[cc * (INTER * 12) + ci * 12 + kk] = w[(crow * INTER + ci) * 9 + kk];
    }
    for (int i = tid; i < INTER * 64; i += 512)
        *(f32x4*)(asf + i * 4) = (f32x4)0.f;
    __syncthreads();
    #pragma unroll
    for (int it = 0; it < 7; it++) {
        int q4 = it * 512 + tid;
        if (q4 < (INTER * P) / 4) {
            float4 vv = *(const float4*)(v_in + q4 * 4);
            float4 gg = *(const float4*)(g + q4 * 4);
            float4 bb = *(const float4*)(b + q4 * 4);
            float va[4] = {vv.x, vv.y, vv.z, vv.w};
            float ga[4] = {gg.x, gg.y, gg.z, gg.w};
            float ba[4] = {bb.x, bb.y, bb.z, bb.w};
            #pragma unroll
            for (int e = 0; e < 4; e++) {
                int idx = q4 * 4 + e;
                int ci = idx / P, p = idx - ci * P;
                int yy = p / WP, xx = p - yy * WP;
                float a = (va[e] - mu) * rstd * ga[e] + ba[e];
                asf[ci * 256 + (yy + 1) * 16 + (xx + 1)] = a > 0.f ? a : 0.f;
            }
        }
    }
    __syncthreads();
    float s = 0.f, ss = 0.f;
    if (tid < 256) {
        int gid = gid0 + tid;
        int c = gid / P, p = gid - c * P, y = p / WP, x = p - (p / WP) * WP;
        const float* wr0 = wlf + (c - cA) * (INTER * 12);
        float v = 0.f;
        for (int ci = 0; ci < INTER; ci++) {
            const float* wi = wr0 + ci * 12;
            const float* a0 = asf + ci * 256 + y * 16 + x;
            v += wi[0]*a0[0]  + wi[1]*a0[1]  + wi[2]*a0[2]
               + wi[3]*a0[16] + wi[4]*a0[17] + wi[5]*a0[18]
               + wi[6]*a0[32] + wi[7]*a0[33] + wi[8]*a0[34];
        }
        v_out[gid] = v;
        s = v; ss = v * v;
    }
    block_reduce2(s, ss, red, tid, 512);
    if (tid == 0) { pstat[pso + 2*bid] = s; pstat[pso + 2*bid + 1] = ss; }
}

// ln2 + scatter-im2col (no LDS, no barriers -> extra threads may exit)
__device__ __forceinline__ void dev_lnsc(int bid, int tid,
                                         const float* __restrict__ v_in,
                                         const float* __restrict__ g,
                                         const float* __restrict__ b,
                                         const float* __restrict__ pstat,
                                         unsigned short* __restrict__ imc) {
    if (tid >= 256) return;
    const float inv = 1.f / (float)(INTER * P);
    int gid = bid * 256 + tid;
    float s0, ss0;
    sum_pstat(pstat, 196, s0, ss0);
    float mu = s0 * inv;
    float var = ss0 * inv - mu * mu;
    float rstd = rsqrtf(var + EPSLN);
    float a = (v_in[gid] - mu) * rstd * g[gid] + b[gid];
    a = a > 0.f ? a : 0.f;
    unsigned short bv = f2bf(a);
    int ci = gid / P, p = gid - ci * P, y = p / WP, x = p - (p / WP) * WP;
    #pragma unroll
    for (int k = 0; k < 9; k++) {
        int yp = y - (k / 3 - 1), xp = x - (k % 3 - 1);
        if (yp >= 0 && yp < HP && xp >= 0 && xp < WP)
            imc[(yp * WP + xp) * KIM + ci * 9 + k] = bv;
    }
}

// gemm_in 512-thread: 128m x 256n tile, 8 waves each 64x64 (acc[4][4]).  LDS: 48 KB
#define GIN_MT 11
#define GIN_NT 49
#define GIN_BLKS (GIN_MT * GIN_NT)            // 539
__device__ __forceinline__ void dev_gemm_in(char* sm, int mb, int nb, int tid,
                                            const unsigned short* __restrict__ A,
                                            const unsigned short* __restrict__ B,
                                            unsigned short* __restrict__ C) {
    unsigned short* As = (unsigned short*)sm;        // 128*64
    unsigned short* Bs = As + 128 * 64;              // 256*64
    int w = tid >> 6, lane = tid & 63, quad = lane >> 4, c16 = lane & 15;
    int m0 = mb * 128, n0 = nb * 256;
    int wm = (w & 1) * 64, wn = (w >> 1) * 64;       // 2m x 4n wave grid
    f32x4 acc[4][4];
    #pragma unroll
    for (int i = 0; i < 4; i++)
        #pragma unroll
        for (int j = 0; j < 4; j++) acc[i][j] = (f32x4)0.f;

    for (int kc = 0; kc < 4; ++kc) {                 // K=256, chunks of 64
        int k0 = kc * 64;
        if (kc) __syncthreads();
        #pragma unroll
        for (int i = tid; i < 1024; i += 512) {      // A: 128 rows x 8 pieces
            int r = i >> 3, s = i & 7, q = (s - (r >> 1)) & 7;
            gl2lds16(A + (size_t)(m0 + r) * DIMC + k0 + q * 8, As + (i & ~63) * 8);
        }
        #pragma unroll
        for (int i = tid; i < 2048; i += 512) {      // B: 256 rows x 8 pieces
            int r = i >> 3, s = i & 7, q = (s - (r >> 1)) & 7;
            gl2lds16(B + (size_t)(n0 + r) * DIMC + k0 + q * 8, Bs + (i & ~63) * 8);
        }
        __syncthreads();
        #pragma unroll
        for (int ks = 0; ks < 2; ++ks) {
            short8 af[4], bfr[4];
            #pragma unroll
            for (int i = 0; i < 4; i++) af[i] = fragld64(As, wm + i * 16 + c16, ks * 4 + quad);
            #pragma unroll
            for (int j = 0; j < 4; j++) bfr[j] = fragld64(Bs, wn + j * 16 + c16, ks * 4 + quad);
            #pragma unroll
            for (int i = 0; i < 4; i++)
                #pragma unroll
                for (int j = 0; j < 4; j++)
                    acc[i][j] = __builtin_amdgcn_mfma_f32_16x16x32_bf16(af[i], bfr[j], acc[i][j], 0, 0, 0);
        }
    }
    #pragma unroll
    for (int j = 0; j < 4; j++) {
        int n = n0 + wn + j * 16 + c16;
        unsigned short* dst = C + (size_t)n * CHN;
        #pragma unroll
        for (int i = 0; i < 4; i++) {
            int m = m0 + wm + i * 16 + quad * 4;
            if (m < CHN) {
                short4v sv;
                sv[0] = (short)f2bf(acc[i][j][0]);
                sv[1] = (short)f2bf(acc[i][j][1]);
                sv[2] = (short)f2bf(acc[i][j][2]);
                sv[3] = (short)f2bf(acc[i][j][3]);
                *(short4v*)(dst + m) = sv;
            }
        }
    }
}

// gemm_wf 512-thread (bid 0..197): wgtT <- wfb x imc.  LDS: 34.8 KB
// 8 waves: waves 0-3 handle f 0..6, waves 4-7 handle f 7..12, m-col = (w&3)*16.
__device__ __forceinline__ void dev_gemm_wf(char* sm, int bid, int tid,
                                            const unsigned short* __restrict__ wfb,
                                            const unsigned short* __restrict__ imc,
                                            unsigned short* __restrict__ wgtT) {
    unsigned short* buf = (unsigned short*)sm;       // 64*64 + 208*64
    unsigned short* As = buf;
    unsigned short* Bs = buf + 64 * 64;
    unsigned short* ot = buf;                        // reused after K-loop
    int w = tid >> 6, lane = tid & 63, quad = lane >> 4, c16 = lane & 15;
    int wq = w & 3;
    int f0 = (w < 4) ? 0 : 7;
    int fN = (w < 4) ? 7 : 6;                        // count of f-tiles for this wave
    int m0 = bid * 64;
    int kk = m0 / MW, ch0 = m0 - kk * MW;
    for (int i = tid; i < 96; i += 512)              // zero B pad rows 196..207
        *(short8*)(Bs + 196 * 64 + i * 8) = (short8)0;
    f32x4 acc[7];
    #pragma unroll
    for (int f = 0; f < 7; f++) acc[f] = (f32x4)0.f;

    for (int kc = 0; kc < 9; ++kc) {                 // K=576, chunks of 64
        int k0 = kc * 64;
        if (kc) __syncthreads();
        {
            int i = tid;                             // A: exactly 512 pieces
            int r = i >> 3, s = i & 7, q = (s - (r >> 1)) & 7;
            gl2lds16(wfb + ((size_t)(kk * MW + ch0 + r)) * KIM + k0 + q * 8, As + (i & ~63) * 8);
        }
        for (int i = tid; i < 1568; i += 512) {      // B: 196 rows x 8 pieces
            int r = i >> 3, s = i & 7, q = (s - (r >> 1)) & 7;
            gl2lds16(imc + (size_t)r * KIM + k0 + q * 8, Bs + (i & ~63) * 8);
        }
        __syncthreads();
        #pragma unroll
        for (int ks = 0; ks < 2; ++ks) {
            short8 af = fragld64(As, wq * 16 + c16, ks * 4 + quad);
            #pragma unroll
            for (int f = 0; f < 7; f++) {
                if (f < fN) {
                    short8 bf = fragld64(Bs, (f0 + f) * 16 + c16, ks * 4 + quad);
                    acc[f] = __builtin_amdgcn_mfma_f32_16x16x32_bf16(af, bf, acc[f], 0, 0, 0);
                }
            }
        }
    }
    __syncthreads();
    #pragma unroll
    for (int f = 0; f < 7; f++) {
        if (f < fN) {
            int p = (f0 + f) * 16 + c16;
            if (p < P) {
                short4v sv;
                sv[0] = (short)f2bf(acc[f][0]);
                sv[1] = (short)f2bf(acc[f][1]);
                sv[2] = (short)f2bf(acc[f][2]);
                sv[3] = (short)f2bf(acc[f][3]);
                *(short4v*)(ot + p * 72 + wq * 16 + quad * 4) = sv;
            }
        }
    }
    __syncthreads();
    int nvalid = CHN - ch0; if (nvalid > 64) nvalid = 64;
    for (int p = tid; p < P; p += 512) {
        const short8* src = (const short8*)(ot + p * 72);
        unsigned short* dst = wgtT + ((size_t)p * 9 + kk) * CHN + ch0;
        #pragma unroll
        for (int j = 0; j < 8; j++)
            if (j * 8 < nvalid) *(short8*)(dst + j * 8) = src[j];
    }
}

// ====================== merged 512-thread launches (single occupancy round) ============
// gemm_in fid bases: mA [0,161), mB [161,321), mC [321,481), mD [481,539)
#define FA 0
#define FB 161
#define FC 321
#define FD 481
#define CONVLN_LDS ((INTER*256 + 3*INTER*12 + 16) * 4)   // 74816 B (>= gin 49152)
#define GIN_LDS    ((128*64 + 256*64) * 2)               // 49152 B (>= wf 34816)
// k_mA filler ranges (streaming work moved out of k_pre):
#define MA_WF0  210                    // wf cast:   891 blocks x 8192 elems = 7299072
#define MA_WO0  1101                   // Wout cast:  22 blocks x 8192 = 180224 = NWOUT
#define MA_IMZ0 1123                   // imc zero:    7 blocks (14112 short8 units)
#define MA_BLKS 1130

extern __shared__ char dynsm[];

__global__ __launch_bounds__(512) void k_mA(const float* v0, const float* g0,
                                            const float* b0, const float* w1,
                                            float* v1, float* pstat,
                                            const unsigned short* Wbin,
                                            const unsigned short* Xt,
                                            unsigned short* h1t,
                                            const float* wf, const float* Wout,
                                            unsigned short* wfb,
                                            unsigned short* Wbout,
                                            unsigned short* imc) {
    int bid = blockIdx.x, tid = threadIdx.x;
    if (bid < 49) {
        dev_convln(dynsm, bid, tid, v0, g0, b0, w1, v1, pstat, 0, 98);
    } else if (bid < MA_WF0) {
        int fid = FA + bid - 49;
        dev_gemm_in(dynsm, fid % GIN_MT, fid / GIN_MT, tid, Wbin, Xt, h1t);
    } else if (bid < MA_WO0) {
        // ---- wf [12240][576] f32 -> wfb [9][1408][576] bf16 (pad rows zero), 4x ILP ----
        int base = (bid - MA_WF0) * 2048;
        #pragma unroll
        for (int k2 = 0; k2 < 4; k2++) {
            int t = base + k2 * 512 + tid;
            int j = t * 4;
            int rowi = j / KIM, q = j - rowi * KIM;
            int kk = rowi / MW, ch = rowi - kk * MW;
            short4v sv = (short4v)0;
            if (ch < CHN) {
                float4 v = *(const float4*)(wf + ((size_t)(ch * 9 + kk)) * KIM + q);
                sv[0] = (short)f2bf(v.x); sv[1] = (short)f2bf(v.y);
                sv[2] = (short)f2bf(v.z); sv[3] = (short)f2bf(v.w);
            }
            *(short4v*)(wfb + j) = sv;
        }
    } else if (bid < MA_IMZ0) {
        // ---- Wout cast: Wbout[o][k] = f2bf(Wout[o*HID+k]) or 0 pad ----
        int base = (bid - MA_WO0) * 2048;
        #pragma unroll
        for (int k2 = 0; k2 < 4; k2++) {
            int t = base + k2 * 512 + tid;
            int j0 = t * 4;
            int o = j0 / KPAD, k = j0 - o * KPAD;  // KPAD,HID %4==0: group uniform
            short4v sv = (short4v)0;
            if (k < HID) {
                float4 v = *(const float4*)(Wout + o * HID + k);
                sv[0] = (short)f2bf(v.x); sv[1] = (short)f2bf(v.y);
                sv[2] = (short)f2bf(v.z); sv[3] = (short)f2bf(v.w);
            }
            *(short4v*)(Wbout + j0) = sv;
        }
    } else {
        // ---- zero imc (scatter-im2col writes only in-bounds entries) ----
        int base = (bid - MA_IMZ0) * 2048;
        #pragma unroll
        for (int k2 = 0; k2 < 4; k2++) {
            int cc = base + k2 * 512 + tid;
            if (cc < (P * KIM) / 8) *(short8*)(imc + cc * 8) = (short8)0;
        }
    }
}
__global__ __launch_bounds__(512) void k_mB(const float* v1, const float* g1,
                                            const float* b1, const float* w2,
                                            float* v2, float* pstat,
                                            const unsigned short* Wbin,
                                            const unsigned short* Xt,
                                            unsigned short* h1t) {
    int bid = blockIdx.x, tid = threadIdx.x;
    if (bid < 49) dev_convln(dynsm, bid, tid, v1, g1, b1, w2, v2, pstat, 98, 196);
    else { int fid = FB + bid - 49; dev_gemm_in(dynsm, fid % GIN_MT, fid / GIN_MT, tid, Wbin, Xt, h1t); }
}
__global__ __launch_bounds__(512) void k_mC(const float* v2, const float* g2,
                                            const float* b2, const float* pstat,
                                            unsigned short* imc,
                                            const unsigned short* Wbin,
                                            const unsigned short* Xt,
                                            unsigned short* h1t) {
    int bid = blockIdx.x, tid = threadIdx.x;
    if (bid < 49) dev_lnsc(bid, tid, v2, g2, b2, pstat, imc);
    else { int fid = FC + bid - 49; dev_gemm_in(dynsm, fid % GIN_MT, fid / GIN_MT, tid, Wbin, Xt, h1t); }
}
// k_mD: blocks [0,198) = gemm_wf; [198, 198+58) = gemm_in slice
__global__ __launch_bounds__(512) void k_mD(const unsigned short* wfb,
                                            const unsigned short* imc,
                                            unsigned short* wgtT,
                                            const unsigned short* Wbin,
                                            const unsigned short* Xt,
                                            unsigned short* h1t) {
    int bid = blockIdx.x, tid = threadIdx.x;
    if (bid < 198) dev_gemm_wf(dynsm, bid, tid, wfb, imc, wgtT);
    else { int fid = FD + bid - 198; dev_gemm_in(dynsm, fid % GIN_MT, fid / GIN_MT, tid, Wbin, Xt, h1t); }
}

// -------- fused tvconv + gelu-gate: 512 threads, 16 batches/block, XCD swizzle ---------
__global__ __launch_bounds__(512) void k_tvg(const unsigned short* __restrict__ h1t,
                                             const unsigned short* __restrict__ wgtT,
                                             unsigned short* __restrict__ hgt) {
    __shared__ __align__(16) unsigned short wl[9 * CHN];   // 24480 B, [k][CHN]
    int id = blockIdx.x;
    int xcd = id & 7, q = id >> 3;                         // grid 800: q in [0,100)
    int p = xcd * 25 + (q % 25);
    int bg = q / 25;                                       // 0..3 (16 batches each)
    if (p >= P) return;
    int b0 = bg * 16, tid = threadIdx.x;
    const unsigned short* wrow = wgtT + (size_t)p * 9 * CHN;
    for (int i = tid * 8; i < 9 * CHN; i += 512 * 8)
        *(short8*)(wl + i) = *(const short8*)(wrow + i);
    int y = p / WP, x = p - (p / WP) * WP;
    int pn[9]; bool pv[9];
    #pragma unroll
    for (int k = 0; k < 9; k++) {
        int yy = y + k / 3 - 1, xx = x + (k % 3) - 1;
        pv[k] = (yy >= 0 && yy < HP && xx >= 0 && xx < WP);
        pn[k] = pv[k] ? yy * WP + xx : 0;
    }
    __syncthreads();
    for (int j = tid; j < 16 * 85; j += 512) {
        int bl = j / 85, c = (j - bl * 85) * 8;
        int b = b0 + bl;
        const unsigned short* hb = h1t + (size_t)b * P * CHN;
        float s1[8], s2[8];
        #pragma unroll
        for (int e = 0; e < 8; e++) { s1[e] = 0.f; s2[e] = 0.f; }
        #pragma unroll
        for (int k = 0; k < 9; k++) {
            if (!pv[k]) continue;
            const unsigned short* hr = hb + (size_t)pn[k] * CHN + c;
            short8 h1v = *(const short8*)hr;
            short8 h2v = *(const short8*)(hr + HID);
            short8 w1v = *(const short8*)(wl + k * CHN + c);
            short8 w2v = *(const short8*)(wl + k * CHN + HID + c);
            #pragma unroll
            for (int e = 0; e < 8; e++) {
                s1[e] += bf2f((unsigned short)w1v[e]) * bf2f((unsigned short)h1v[e]);
                s2[e] += bf2f((unsigned short)w2v[e]) * bf2f((unsigned short)h2v[e]);
            }
        }
        short8 o;
        #pragma unroll
        for (int e = 0; e < 8; e++) {
            float gl = 0.5f * s1[e] * (1.f + erff(s1[e] * 0.70710678118654752f));
            o[e] = (short)f2bf(gl * s2[e]);
        }
        *(short8*)(hgt + ((size_t)b * P + p) * KPAD + c) = o;
    }
    if (tid < 48) {
        int bl = tid / 3, z = (tid - bl * 3) * 8;
        *(short8*)(hgt + ((size_t)(b0 + bl) * P + p) * KPAD + HID + z) = (short8)0;
    }
}

// ---------------- tiled MFMA GEMM 2 (BK=64): out[m][n] = sum_k Wbout[m][k] hgt[n][k] ------
__global__ __launch_bounds__(256) void k_gemm_out(const unsigned short* __restrict__ A,
                                                  const unsigned short* __restrict__ B,
                                                  float* __restrict__ out) {
    __shared__ __align__(16) unsigned short As[64 * 64];     // 8 KB
    __shared__ __align__(16) unsigned short Bs[128 * 64];    // 16 KB
    int tid = threadIdx.x;
    int w = tid >> 6, lane = tid & 63, quad = lane >> 4, c16 = lane & 15;
    int m0 = blockIdx.x * 64, n0 = blockIdx.y * 128;
    int wm = (w & 1) * 32, wn = (w >> 1) * 64;
    f32x4 acc[2][4];
    #pragma unroll
    for (int i = 0; i < 2; i++)
        #pragma unroll
        for (int j = 0; j < 4; j++) acc[i][j] = (f32x4)0.f;

    for (int kc = 0; kc < 11; ++kc) {                        // K=704, chunks of 64
        int k0 = kc * 64;
        if (kc) __syncthreads();
        #pragma unroll
        for (int i = tid; i < 512; i += 256) {               // A: 64 rows x 8 pieces
            int r = i >> 3, s = i & 7, q = (s - (r >> 1)) & 7;
            gl2lds16(A + (size_t)(m0 + r) * KPAD + k0 + q * 8, As + (i & ~63) * 8);
        }
        #pragma unroll
        for (int i = tid; i < 1024; i += 256) {              // B: 128 rows x 8 pieces
            int r = i >> 3, s = i & 7, q = (s - (r >> 1)) & 7;
            gl2lds16(B + (size_t)(n0 + r) * KPAD + k0 + q * 8, Bs + (i & ~63) * 8);
        }
        __syncthreads();
        #pragma unroll
        for (int ks = 0; ks < 2; ++ks) {
            short8 af[2], bfr[4];
            #pragma unroll
            for (int i = 0; i < 2; i++) af[i] = fragld64(As, wm + i * 16 + c16, ks * 4 + quad);
            #pragma unroll
            for (int j = 0; j < 4; j++) bfr[j] = fragld64(Bs, wn + j * 16 + c16, ks * 4 + quad);
            #pragma unroll
            for (int i = 0; i < 2; i++)
                #pragma unroll
                for (int j = 0; j < 4; j++)
                    acc[i][j] = __builtin_amdgcn_mfma_f32_16x16x32_bf16(af[i], bfr[j], acc[i][j], 0, 0, 0);
        }
    }
    #pragma unroll
    for (int j = 0; j < 4; j++) {
        int n = n0 + wn + j * 16 + c16;
        int b = n / P, pp = n - b * P;
        #pragma unroll
        for (int i = 0; i < 2; i++) {
            int m = m0 + wm + i * 16 + quad * 4;
            #pragma unroll
            for (int r = 0; r < 4; r++)
                out[((size_t)b * DIMC + m + r) * P + pp] = acc[i][j][r];
        }
    }
}

extern "C" void kernel_launch(void* const* d_in, const int* in_sizes, int n_in,
                              void* d_out, int out_size, void* d_ws, size_t ws_size,
                              hipStream_t stream) {
    (void)in_sizes; (void)n_in; (void)out_size; (void)ws_size;
    const float* x     = (const float*)d_in[0];
    const float* W_in  = (const float*)d_in[1];
    const float* posi  = (const float*)d_in[2];
    const float* w0    = (const float*)d_in[3];
    const float* g0    = (const float*)d_in[4];
    const float* b0    = (const float*)d_in[5];
    const float* w1    = (const float*)d_in[6];
    const float* g1    = (const float*)d_in[7];
    const float* b1    = (const float*)d_in[8];
    const float* w2    = (const float*)d_in[9];
    const float* g2    = (const float*)d_in[10];
    const float* b2    = (const float*)d_in[11];
    const float* wf    = (const float*)d_in[12];
    const float* W_out = (const float*)d_in[13];
    float* out = (float*)d_out;
    char* ws = (char*)d_ws;

    unsigned short* Wbin  = (unsigned short*)(ws + OFS_WBIN);
    unsigned short* Wbout = (unsigned short*)(ws + OFS_WBOUT);
    unsigned short* Xt    = (unsigned short*)(ws + OFS_XT);
    float*          v0    = (float*)(ws + OFS_V0);
    float*          v1    = (float*)(ws + OFS_V1);
    float*          v2    = (float*)(ws + OFS_V2);
    float*          pstat = (float*)(ws + OFS_PST);
    unsigned short* wgtT  = (unsigned short*)(ws + OFS_WGTT);
    unsigned short* h1t   = (unsigned short*)(ws + OFS_H1T);
    unsigned short* hgt   = (unsigned short*)(ws + OFS_HGT);
    unsigned short* imc   = (unsigned short*)(ws + OFS_IMC);
    unsigned short* wfb   = (unsigned short*)(ws + OFS_WFB);

    // 1: slim preamble (only what mA needs: conv0, Xt, Wbin)
    k_pre<<<PRE_BLKS, 256, 0, stream>>>(W_in, x, posi, w0, Wbin, Xt, v0, pstat);
    // 2: convln1 ∥ gemm_in slice ∥ wf/Wout casts + imc zero (late-consumed streaming)
    k_mA<<<MA_BLKS, 512, CONVLN_LDS, stream>>>(v0, g0, b0, w1, v1, pstat, Wbin, Xt, h1t,
                                               wf, W_out, wfb, Wbout, imc);
    // 3-4: convln2 / lnsc ∥ gemm_in slices
    k_mB<<<49 + (FC - FB), 512, CONVLN_LDS, stream>>>(v1, g1, b1, w2, v2, pstat, Wbin, Xt, h1t);
    k_mC<<<49 + (FD - FC), 512, CONVLN_LDS, stream>>>(v2, g2, b2, pstat, imc, Wbin, Xt, h1t);
    // 5: gemm_wf ∥ remaining gemm_in blocks
    k_mD<<<198 + (GIN_BLKS - FD), 512, GIN_LDS, stream>>>(wfb, imc, wgtT, Wbin, Xt, h1t);
    // 6-7: tvconv+gate (512 threads, 16 batches/block), output GEMM
    k_tvg     <<<800, 512, 0, stream>>>(h1t, wgtT, hgt);
    k_gemm_out<<<dim3(DIMC/64, (BATCH*P)/128), 256, 0, stream>>>(Wbout, hgt, out);
}